// Round 15
// baseline (2085.456 us; speedup 1.0000x reference)
//
#include <hip/hip_runtime.h>
#include <math.h>

#define TOKENS 8192
#define DM 512
#define TD 1536
#define SEQ 1024
#define NPATH 16
#define TOPK 8

typedef __bf16 bf16x8v __attribute__((ext_vector_type(8)));
typedef __bf16 bf16x4v __attribute__((ext_vector_type(4)));
typedef float f32x4v __attribute__((ext_vector_type(4)));
typedef unsigned short u16x8 __attribute__((ext_vector_type(8)));

__device__ __forceinline__ void gload_lds16(const void* gp, unsigned lds_byte_off) {
    __builtin_amdgcn_global_load_lds(
        (const __attribute__((address_space(1))) unsigned int*)(uintptr_t)gp,
        (__attribute__((address_space(3))) unsigned int*)(uintptr_t)lds_byte_off,
        16, 0, 0);
}

// ---------------------------------------------------------------------------
// fp32 NT GEMM: C = alpha*(A@B^T) + bias, optional relu.
// 128x128 tile, BK=16, 256 threads, 8x8 micro-tile.
// PREF=1: register double-buffer — pays when blocks/CU <= ~1 (ctxOut, r_w1)
// or K is short (batched QK^T). PREF=0: plain loop, better occupancy for the
// compute-rich 3-blocks/CU ctxQKV.
// zmode=1: batched router QK^T (z = b*2+h over qkv buffer, C = S + z*S*S).
// ---------------------------------------------------------------------------
template <int PREF>
__global__ __launch_bounds__(256)
void gemm_f32_nt(const float* __restrict__ A, const float* __restrict__ B,
                 const float* __restrict__ bias, float* __restrict__ C,
                 int M, int N, int K, int lda, int ldb, int ldc,
                 float alpha, int relu, int zmode)
{
    __shared__ float As[16][132];
    __shared__ float Bs[16][132];
    if (zmode == 1) {
        const int z = blockIdx.z, bb = z >> 1, hh = z & 1;
        A += (size_t)bb * SEQ * TD + hh * 256;
        B += (size_t)bb * SEQ * TD + 512 + hh * 256;
        C += (size_t)z * SEQ * SEQ;
    }
    const int tid = threadIdx.x;
    const int bm = blockIdx.y << 7, bn = blockIdx.x << 7;
    const int tx4 = (tid & 15) << 2, ty4 = ((tid >> 4) & 15) << 2;
    float acc[8][8] = {};

    if constexpr (PREF) {
        const int srow = tid >> 2, skc4 = (tid & 3) << 2;
        const float* Ap = A + (size_t)(bm + srow) * lda + skc4;
        const float* Ap2 = A + (size_t)(bm + 64 + srow) * lda + skc4;
        const float* Bp = B + (size_t)(bn + srow) * ldb + skc4;
        const float* Bp2 = B + (size_t)(bn + 64 + srow) * ldb + skc4;
        float4 pa0 = *(const float4*)Ap,  pa1 = *(const float4*)Ap2;
        float4 pb0 = *(const float4*)Bp,  pb1 = *(const float4*)Bp2;
        for (int k0 = 0; k0 < K; k0 += 16) {
            __syncthreads();
            As[skc4 + 0][srow] = pa0.x; As[skc4 + 1][srow] = pa0.y;
            As[skc4 + 2][srow] = pa0.z; As[skc4 + 3][srow] = pa0.w;
            As[skc4 + 0][64 + srow] = pa1.x; As[skc4 + 1][64 + srow] = pa1.y;
            As[skc4 + 2][64 + srow] = pa1.z; As[skc4 + 3][64 + srow] = pa1.w;
            Bs[skc4 + 0][srow] = pb0.x; Bs[skc4 + 1][srow] = pb0.y;
            Bs[skc4 + 2][srow] = pb0.z; Bs[skc4 + 3][srow] = pb0.w;
            Bs[skc4 + 0][64 + srow] = pb1.x; Bs[skc4 + 1][64 + srow] = pb1.y;
            Bs[skc4 + 2][64 + srow] = pb1.z; Bs[skc4 + 3][64 + srow] = pb1.w;
            if (k0 + 16 < K) {
                pa0 = *(const float4*)(Ap + k0 + 16);
                pa1 = *(const float4*)(Ap2 + k0 + 16);
                pb0 = *(const float4*)(Bp + k0 + 16);
                pb1 = *(const float4*)(Bp2 + k0 + 16);
            }
            __syncthreads();
#pragma unroll
            for (int kk = 0; kk < 16; ++kk) {
                const float4 a0 = *(const float4*)&As[kk][ty4];
                const float4 a1 = *(const float4*)&As[kk][64 + ty4];
                const float4 b0 = *(const float4*)&Bs[kk][tx4];
                const float4 b1 = *(const float4*)&Bs[kk][64 + tx4];
                const float aa[8] = {a0.x, a0.y, a0.z, a0.w, a1.x, a1.y, a1.z, a1.w};
                const float bb[8] = {b0.x, b0.y, b0.z, b0.w, b1.x, b1.y, b1.z, b1.w};
#pragma unroll
                for (int i = 0; i < 8; ++i)
#pragma unroll
                    for (int j = 0; j < 8; ++j)
                        acc[i][j] = fmaf(aa[i], bb[j], acc[i][j]);
            }
        }
    } else {
        for (int k0 = 0; k0 < K; k0 += 16) {
            __syncthreads();
#pragma unroll
            for (int it = 0; it < 2; ++it) {
                const int u = (it << 8) + tid;
                const int row = u >> 2, kc4 = (u & 3) << 2;
                const float4 av = *(const float4*)(A + (size_t)(bm + row) * lda + k0 + kc4);
                As[kc4 + 0][row] = av.x; As[kc4 + 1][row] = av.y;
                As[kc4 + 2][row] = av.z; As[kc4 + 3][row] = av.w;
                const float4 bv = *(const float4*)(B + (size_t)(bn + row) * ldb + k0 + kc4);
                Bs[kc4 + 0][row] = bv.x; Bs[kc4 + 1][row] = bv.y;
                Bs[kc4 + 2][row] = bv.z; Bs[kc4 + 3][row] = bv.w;
            }
            __syncthreads();
#pragma unroll
            for (int kk = 0; kk < 16; ++kk) {
                const float4 a0 = *(const float4*)&As[kk][ty4];
                const float4 a1 = *(const float4*)&As[kk][64 + ty4];
                const float4 b0 = *(const float4*)&Bs[kk][tx4];
                const float4 b1 = *(const float4*)&Bs[kk][64 + tx4];
                const float aa[8] = {a0.x, a0.y, a0.z, a0.w, a1.x, a1.y, a1.z, a1.w};
                const float bb[8] = {b0.x, b0.y, b0.z, b0.w, b1.x, b1.y, b1.z, b1.w};
#pragma unroll
                for (int i = 0; i < 8; ++i)
#pragma unroll
                    for (int j = 0; j < 8; ++j)
                        acc[i][j] = fmaf(aa[i], bb[j], acc[i][j]);
            }
        }
    }

    float bcol[8] = {};
    if (bias) {
        const float4 bL = *(const float4*)(bias + bn + tx4);
        const float4 bH = *(const float4*)(bias + bn + 64 + tx4);
        bcol[0] = bL.x; bcol[1] = bL.y; bcol[2] = bL.z; bcol[3] = bL.w;
        bcol[4] = bH.x; bcol[5] = bH.y; bcol[6] = bH.z; bcol[7] = bH.w;
    }
#pragma unroll
    for (int i = 0; i < 8; ++i) {
        const int row = bm + ((i < 4) ? (ty4 + i) : (64 + ty4 + i - 4));
        float* cp = C + (size_t)row * ldc + bn;
        float v[8];
#pragma unroll
        for (int j = 0; j < 8; ++j) {
            v[j] = alpha * acc[i][j] + bcol[j];
            if (relu) v[j] = fmaxf(v[j], 0.f);
        }
        *(float4*)(cp + tx4) = make_float4(v[0], v[1], v[2], v[3]);
        *(float4*)(cp + 64 + tx4) = make_float4(v[4], v[5], v[6], v[7]);
    }
}

// ---------------------------------------------------------------------------
// fp32 NN GEMM (router PV), batched z; register prefetch (1 block/CU).
// ---------------------------------------------------------------------------
__global__ __launch_bounds__(256)
void gemm_f32_pv(const float* __restrict__ Sb, const float* __restrict__ qkv,
                 float* __restrict__ obuf)
{
    __shared__ float As[16][132];
    __shared__ float Bs[16][128];
    const int z = blockIdx.z, bb = z >> 1, hh = z & 1;
    const float* A = Sb + (size_t)z * SEQ * SEQ;
    const float* B = qkv + (size_t)bb * SEQ * TD + 1024 + hh * 256;
    float* C = obuf + (size_t)bb * SEQ * 512 + hh * 256;
    const int tid = threadIdx.x;
    const int bm = blockIdx.y << 7, bn = blockIdx.x << 7;
    const int tx4 = (tid & 15) << 2, ty4 = ((tid >> 4) & 15) << 2;
    const int ar = tid >> 2, ak4 = (tid & 3) << 2;
    const int br = tid >> 5, bn4 = (tid & 31) << 2;
    const float* ApA  = A + (size_t)(bm + ar) * SEQ + ak4;
    const float* ApA2 = A + (size_t)(bm + 64 + ar) * SEQ + ak4;
    const float* BpB  = B + (size_t)br * TD + bn + bn4;
    const float* BpB2 = B + (size_t)(8 + br) * TD + bn + bn4;

    float4 a0 = *(const float4*)ApA, a1 = *(const float4*)ApA2;
    float4 b0 = *(const float4*)BpB, b1 = *(const float4*)BpB2;

    float acc[8][8] = {};
    for (int k0 = 0; k0 < SEQ; k0 += 16) {
        __syncthreads();
        As[ak4 + 0][ar] = a0.x; As[ak4 + 1][ar] = a0.y;
        As[ak4 + 2][ar] = a0.z; As[ak4 + 3][ar] = a0.w;
        As[ak4 + 0][64 + ar] = a1.x; As[ak4 + 1][64 + ar] = a1.y;
        As[ak4 + 2][64 + ar] = a1.z; As[ak4 + 3][64 + ar] = a1.w;
        *(float4*)&Bs[br][bn4] = b0;
        *(float4*)&Bs[8 + br][bn4] = b1;
        if (k0 + 16 < SEQ) {
            a0 = *(const float4*)(ApA + k0 + 16);
            a1 = *(const float4*)(ApA2 + k0 + 16);
            b0 = *(const float4*)(BpB + (size_t)(k0 + 16) * TD);
            b1 = *(const float4*)(BpB2 + (size_t)(k0 + 16) * TD);
        }
        __syncthreads();
#pragma unroll
        for (int kk = 0; kk < 16; ++kk) {
            const float4 A0 = *(const float4*)&As[kk][ty4];
            const float4 A1 = *(const float4*)&As[kk][64 + ty4];
            const float4 B0 = *(const float4*)&Bs[kk][tx4];
            const float4 B1 = *(const float4*)&Bs[kk][64 + tx4];
            const float aa[8] = {A0.x, A0.y, A0.z, A0.w, A1.x, A1.y, A1.z, A1.w};
            const float bb[8] = {B0.x, B0.y, B0.z, B0.w, B1.x, B1.y, B1.z, B1.w};
#pragma unroll
            for (int i = 0; i < 8; ++i)
#pragma unroll
                for (int j = 0; j < 8; ++j)
                    acc[i][j] = fmaf(aa[i], bb[j], acc[i][j]);
        }
    }
#pragma unroll
    for (int i = 0; i < 8; ++i) {
        const int row = bm + ((i < 4) ? (ty4 + i) : (64 + ty4 + i - 4));
        float* cp = C + (size_t)row * 512 + bn;
        *(float4*)(cp + tx4) = make_float4(acc[i][0], acc[i][1], acc[i][2], acc[i][3]);
        *(float4*)(cp + 64 + tx4) = make_float4(acc[i][4], acc[i][5], acc[i][6], acc[i][7]);
    }
}

// Row softmax over 1024 cols, in-place. One wave per row.
__global__ __launch_bounds__(256)
void softmax_rows(float* __restrict__ S_)
{
    const int row = blockIdx.x * 4 + (threadIdx.x >> 6);
    const int lane = threadIdx.x & 63;
    float* rp = S_ + (size_t)row * 1024 + lane * 16;
    float4 v[4];
#pragma unroll
    for (int i = 0; i < 4; ++i) v[i] = *(const float4*)(rp + i * 4);
    float mx = -INFINITY;
#pragma unroll
    for (int i = 0; i < 4; ++i)
        mx = fmaxf(mx, fmaxf(fmaxf(v[i].x, v[i].y), fmaxf(v[i].z, v[i].w)));
#pragma unroll
    for (int off = 1; off < 64; off <<= 1) mx = fmaxf(mx, __shfl_xor(mx, off));
    float sum = 0.f;
#pragma unroll
    for (int i = 0; i < 4; ++i) {
        v[i].x = __expf(v[i].x - mx); v[i].y = __expf(v[i].y - mx);
        v[i].z = __expf(v[i].z - mx); v[i].w = __expf(v[i].w - mx);
        sum += v[i].x + v[i].y + v[i].z + v[i].w;
    }
#pragma unroll
    for (int off = 1; off < 64; off <<= 1) sum += __shfl_xor(sum, off);
    const float inv = 1.f / sum;
#pragma unroll
    for (int i = 0; i < 4; ++i) {
        v[i].x *= inv; v[i].y *= inv; v[i].z *= inv; v[i].w *= inv;
        *(float4*)(rp + i * 4) = v[i];
    }
}

// ---------------------------------------------------------------------------
// fp32 GEMM 64x64 (small router layers r_w2/r_w3).
// ---------------------------------------------------------------------------
__global__ __launch_bounds__(256)
void gemm_f32(const float* __restrict__ A, const float* __restrict__ W,
              const float* __restrict__ bias, float* __restrict__ C,
              int M, int N, int K, int relu)
{
    __shared__ float As[16][64];
    __shared__ float Bs[16][64];
    const int bm = blockIdx.y << 6;
    const int bn = blockIdx.x << 6;
    const int tid = threadIdx.x;
    const int tx = tid & 15, ty = tid >> 4;
    const int lr = tid >> 2;
    const int lc = (tid & 3) << 2;
    float acc[4][4] = {};
    for (int k0 = 0; k0 < K; k0 += 16) {
        float4 av = *(const float4*)(A + (size_t)(bm + lr) * K + (k0 + lc));
        float4 bv = make_float4(0.f, 0.f, 0.f, 0.f);
        const int wr = bn + lr;
        if (wr < N) bv = *(const float4*)(W + (size_t)wr * K + (k0 + lc));
        __syncthreads();
        As[lc + 0][lr] = av.x; As[lc + 1][lr] = av.y;
        As[lc + 2][lr] = av.z; As[lc + 3][lr] = av.w;
        Bs[lc + 0][lr] = bv.x; Bs[lc + 1][lr] = bv.y;
        Bs[lc + 2][lr] = bv.z; Bs[lc + 3][lr] = bv.w;
        __syncthreads();
#pragma unroll
        for (int kk = 0; kk < 16; ++kk) {
            const float4 a4 = *(const float4*)(&As[kk][ty << 2]);
            const float4 b4 = *(const float4*)(&Bs[kk][tx << 2]);
            const float a[4] = {a4.x, a4.y, a4.z, a4.w};
            const float b[4] = {b4.x, b4.y, b4.z, b4.w};
#pragma unroll
            for (int i = 0; i < 4; ++i)
#pragma unroll
                for (int j = 0; j < 4; ++j)
                    acc[i][j] = fmaf(a[i], b[j], acc[i][j]);
        }
    }
#pragma unroll
    for (int i = 0; i < 4; ++i) {
        const int m = bm + (ty << 2) + i;
#pragma unroll
        for (int j = 0; j < 4; ++j) {
            const int n = bn + (tx << 2) + j;
            if (n < N) {
                float v = acc[i][j] + bias[n];
                if (relu) v = fmaxf(v, 0.f);
                C[(size_t)m * N + n] = v;
            }
        }
    }
}

// ---------------------------------------------------------------------------
// fp32 flash attention fallback (router ctx, DH=256) — used when ws is small.
// ---------------------------------------------------------------------------
template <int DH>
__global__ __launch_bounds__(256)
void flash_attn(const float* __restrict__ qkv, float* __restrict__ O,
                int H, float scale)
{
    constexpr int NU = DH / 64;
    __shared__ float Qs[32][DH + 4];
    __shared__ float Ks[32][DH + 4];
    __shared__ float Vs[32][DH + 4];
    __shared__ float Ps[32][33];
    const int tid = threadIdx.x;
    const int g2 = tid & 15;
    const int rs = tid >> 4;
    const int bh = blockIdx.y;
    const int b = bh / H, h = bh - b * H;
    const int rb = blockIdx.x << 5;
    const float* qb = qkv + (size_t)b * SEQ * TD + (size_t)h * DH;
    const float* kb = qb + DM;
    const float* vb = qb + 2 * DM;

    for (int idx = tid; idx < 32 * (DH / 4); idx += 256) {
        const int rr = idx / (DH / 4);
        const int dp = (idx - rr * (DH / 4)) << 2;
        float4 v = *(const float4*)(qb + (size_t)(rb + rr) * TD + dp);
        v.x *= scale; v.y *= scale; v.z *= scale; v.w *= scale;
        *(float4*)&Qs[rr][dp] = v;
    }
    float m0 = -INFINITY, m1 = -INFINITY, l0 = 0.f, l1 = 0.f;
    float4 o0[NU], o1[NU];
#pragma unroll
    for (int u = 0; u < NU; ++u) {
        o0[u] = make_float4(0.f, 0.f, 0.f, 0.f);
        o1[u] = make_float4(0.f, 0.f, 0.f, 0.f);
    }
    __syncthreads();

    for (int kt = 0; kt < SEQ; kt += 32) {
        for (int idx = tid; idx < 32 * (DH / 4); idx += 256) {
            const int rr = idx / (DH / 4);
            const int dp = (idx - rr * (DH / 4)) << 2;
            *(float4*)&Ks[rr][dp] = *(const float4*)(kb + (size_t)(kt + rr) * TD + dp);
            *(float4*)&Vs[rr][dp] = *(const float4*)(vb + (size_t)(kt + rr) * TD + dp);
        }
        __syncthreads();
        float s00 = 0.f, s01 = 0.f, s10 = 0.f, s11 = 0.f;
        const int cA = g2, cB = g2 + 16;
#pragma unroll 8
        for (int i = 0; i < DH; i += 4) {
            const float4 q0 = *(const float4*)&Qs[rs][i];
            const float4 q1 = *(const float4*)&Qs[rs + 16][i];
            const float4 k0 = *(const float4*)&Ks[cA][i];
            const float4 k1 = *(const float4*)&Ks[cB][i];
            s00 += q0.x * k0.x + q0.y * k0.y + q0.z * k0.z + q0.w * k0.w;
            s01 += q0.x * k1.x + q0.y * k1.y + q0.z * k1.z + q0.w * k1.w;
            s10 += q1.x * k0.x + q1.y * k0.y + q1.z * k0.z + q1.w * k0.w;
            s11 += q1.x * k1.x + q1.y * k1.y + q1.z * k1.z + q1.w * k1.w;
        }
        float ml0 = fmaxf(s00, s01), ml1 = fmaxf(s10, s11);
#pragma unroll
        for (int off = 1; off < 16; off <<= 1) {
            ml0 = fmaxf(ml0, __shfl_xor(ml0, off));
            ml1 = fmaxf(ml1, __shfl_xor(ml1, off));
        }
        const float n0 = fmaxf(m0, ml0), n1 = fmaxf(m1, ml1);
        const float f0 = __expf(m0 - n0), f1 = __expf(m1 - n1);
        const float p00 = __expf(s00 - n0), p01 = __expf(s01 - n0);
        const float p10 = __expf(s10 - n1), p11 = __expf(s11 - n1);
        float sum0 = p00 + p01, sum1 = p10 + p11;
#pragma unroll
        for (int off = 1; off < 16; off <<= 1) {
            sum0 += __shfl_xor(sum0, off);
            sum1 += __shfl_xor(sum1, off);
        }
        l0 = l0 * f0 + sum0; l1 = l1 * f1 + sum1;
        m0 = n0; m1 = n1;
#pragma unroll
        for (int u = 0; u < NU; ++u) {
            o0[u].x *= f0; o0[u].y *= f0; o0[u].z *= f0; o0[u].w *= f0;
            o1[u].x *= f1; o1[u].y *= f1; o1[u].z *= f1; o1[u].w *= f1;
        }
        Ps[rs][cA] = p00; Ps[rs][cB] = p01;
        Ps[rs + 16][cA] = p10; Ps[rs + 16][cB] = p11;
        __syncthreads();
#pragma unroll 4
        for (int c = 0; c < 32; ++c) {
            const float pv0 = Ps[rs][c];
            const float pv1 = Ps[rs + 16][c];
#pragma unroll
            for (int u = 0; u < NU; ++u) {
                const float4 v4 = *(const float4*)&Vs[c][(g2 << 2) + (u << 6)];
                o0[u].x = fmaf(pv0, v4.x, o0[u].x);
                o0[u].y = fmaf(pv0, v4.y, o0[u].y);
                o0[u].z = fmaf(pv0, v4.z, o0[u].z);
                o0[u].w = fmaf(pv0, v4.w, o0[u].w);
                o1[u].x = fmaf(pv1, v4.x, o1[u].x);
                o1[u].y = fmaf(pv1, v4.y, o1[u].y);
                o1[u].z = fmaf(pv1, v4.z, o1[u].z);
                o1[u].w = fmaf(pv1, v4.w, o1[u].w);
            }
        }
        __syncthreads();
    }
    const float i0 = 1.f / l0, i1 = 1.f / l1;
    float* ob0 = O + (size_t)b * SEQ * DM + (size_t)(rb + rs) * DM + h * DH;
    float* ob1 = ob0 + (size_t)16 * DM;
#pragma unroll
    for (int u = 0; u < NU; ++u) {
        float4 w0 = o0[u];
        w0.x *= i0; w0.y *= i0; w0.z *= i0; w0.w *= i0;
        *(float4*)(ob0 + (g2 << 2) + (u << 6)) = w0;
        float4 w1 = o1[u];
        w1.x *= i1; w1.y *= i1; w1.z *= i1; w1.w *= i1;
        *(float4*)(ob1 + (g2 << 2) + (u << 6)) = w1;
    }
}

// ---------------------------------------------------------------------------
// Router epilogue + loss (fp32-exact)
// ---------------------------------------------------------------------------
__global__ __launch_bounds__(256)
void router_epilogue(const float* __restrict__ scores, float* __restrict__ freq,
                     float* __restrict__ weights)
{
    const int t = blockIdx.x * 256 + threadIdx.x;
    float s[NPATH];
#pragma unroll
    for (int i = 0; i < NPATH; ++i) s[i] = scores[(size_t)t * NPATH + i];
    float mx = s[0];
#pragma unroll
    for (int i = 1; i < NPATH; ++i) mx = fmaxf(mx, s[i]);
    float p[NPATH];
    float sum = 0.f;
#pragma unroll
    for (int i = 0; i < NPATH; ++i) { p[i] = expf(s[i] - mx); sum += p[i]; }
    const float inv = 1.f / sum;
#pragma unroll
    for (int i = 0; i < NPATH; ++i) p[i] *= inv;
#pragma unroll
    for (int i = 0; i < NPATH; ++i) {
        float v = p[i];
        for (int off = 32; off >= 1; off >>= 1) v += __shfl_xor(v, off);
        if ((threadIdx.x & 63) == 0) atomicAdd(&freq[i], v);
    }
    unsigned used = 0u;
    float topv[TOPK];
    int topi[TOPK];
    float wsum = 0.f;
#pragma unroll
    for (int k = 0; k < TOPK; ++k) {
        float best = -1.f; int bi = 0;
#pragma unroll
        for (int i = 0; i < NPATH; ++i) {
            if (!((used >> i) & 1u) && p[i] > best) { best = p[i]; bi = i; }
        }
        used |= 1u << bi;
        topv[k] = best; topi[k] = bi;
        wsum += best;
    }
    const float winv = 1.f / (wsum + 1e-8f);
    float w[NPATH];
#pragma unroll
    for (int i = 0; i < NPATH; ++i) w[i] = 0.f;
#pragma unroll
    for (int k = 0; k < TOPK; ++k) w[topi[k]] = topv[k] * winv;
#pragma unroll
    for (int i = 0; i < NPATH; ++i) weights[(size_t)t * NPATH + i] = w[i];
}

__global__ void glbl_loss_kernel(const float* __restrict__ freq, float* __restrict__ out)
{
    if (threadIdx.x == 0 && blockIdx.x == 0) {
        float acc = 0.f;
        for (int i = 0; i < NPATH; ++i) {
            const float f = freq[i] * (1.f / (float)TOKENS);
            acc += f * f;
        }
        out[0] = (float)NPATH * acc;
    }
}

__global__ __launch_bounds__(256)
void cast_f32_bf16(const float* __restrict__ src, __bf16* __restrict__ dst, int n)
{
    const int i = (blockIdx.x * 256 + threadIdx.x) * 4;
    if (i < n) {
        const float4 v = *(const float4*)(src + i);
        bf16x4v o;
        o[0] = (__bf16)v.x; o[1] = (__bf16)v.y; o[2] = (__bf16)v.z; o[3] = (__bf16)v.w;
        *(bf16x4v*)(dst + i) = o;
    }
}

// ---------------------------------------------------------------------------
// bf16 MFMA GEMM (m97): C = A@B^T + bias; cols<512 (Q) scaled x0.125.
// ---------------------------------------------------------------------------
__global__ __launch_bounds__(256)
void gemm_bf16_qkv(const __bf16* __restrict__ A, const __bf16* __restrict__ B,
                   const float* __restrict__ bias, __bf16* __restrict__ C,
                   int N, int K)
{
    __shared__ __attribute__((aligned(16))) __bf16 As[128 * 32];
    __shared__ __attribute__((aligned(16))) __bf16 Bs[128 * 32];
    const int tid = threadIdx.x;
    const int l = tid & 63, w = tid >> 6;
    const int wr = w >> 1, wc = w & 1;
    const int a16 = l & 15, g = l >> 4;
    const int bm = blockIdx.y << 7, bn = blockIdx.x << 7;
    const unsigned asA = (unsigned)(uintptr_t)(void*)&As[0];
    const unsigned asB = (unsigned)(uintptr_t)(void*)&Bs[0];

    f32x4v acc[4][4] = {};
    for (int k0 = 0; k0 < K; k0 += 32) {
        __syncthreads();
#pragma unroll
        for (int it = 0; it < 2; ++it) {
            const int u = it * 256 + tid;
            const int row = u >> 2, cc = u & 3;
            const unsigned dst = (unsigned)((it * 256 + w * 64) * 16);
            gload_lds16(A + (size_t)(bm + row) * K + k0 + cc * 8, asA + dst);
            gload_lds16(B + (size_t)(bn + row) * K + k0 + cc * 8, asB + dst);
        }
        __syncthreads();
        bf16x8v af[4], bf[4];
#pragma unroll
        for (int m = 0; m < 4; ++m)
            af[m] = *(const bf16x8v*)&As[(wr * 64 + m * 16 + a16) * 32 + g * 8];
#pragma unroll
        for (int n = 0; n < 4; ++n)
            bf[n] = *(const bf16x8v*)&Bs[(wc * 64 + n * 16 + a16) * 32 + g * 8];
#pragma unroll
        for (int m = 0; m < 4; ++m)
#pragma unroll
            for (int n = 0; n < 4; ++n)
                acc[m][n] = __builtin_amdgcn_mfma_f32_16x16x32_bf16(af[m], bf[n], acc[m][n], 0, 0, 0);
    }
#pragma unroll
    for (int n = 0; n < 4; ++n) {
        const int col = bn + wc * 64 + n * 16 + a16;
        const float bv = bias[col];
        const float sc = (col < DM) ? 0.125f : 1.0f;   // fold 1/sqrt(64) into Q
#pragma unroll
        for (int m = 0; m < 4; ++m) {
            const int row0 = bm + wr * 64 + m * 16 + g * 4;
#pragma unroll
            for (int r = 0; r < 4; ++r)
                C[(size_t)(row0 + r) * N + col] = (__bf16)((acc[m][n][r] + bv) * sc);
        }
    }
}

__global__ __launch_bounds__(256)
void gemm_bf16_out(const __bf16* __restrict__ A, const __bf16* __restrict__ B,
                   const float* __restrict__ bias, const float* __restrict__ wts,
                   float* __restrict__ out, int path, int first)
{
    __shared__ __attribute__((aligned(16))) __bf16 As[128 * 32];
    __shared__ __attribute__((aligned(16))) __bf16 Bs[128 * 32];
    const int tid = threadIdx.x;
    const int l = tid & 63, w = tid >> 6;
    const int wr = w >> 1, wc = w & 1;
    const int a16 = l & 15, g = l >> 4;
    const int bm = blockIdx.y << 7, bn = blockIdx.x << 7;
    const unsigned asA = (unsigned)(uintptr_t)(void*)&As[0];
    const unsigned asB = (unsigned)(uintptr_t)(void*)&Bs[0];

    f32x4v acc[4][4] = {};
    for (int k0 = 0; k0 < DM; k0 += 32) {
        __syncthreads();
#pragma unroll
        for (int it = 0; it < 2; ++it) {
            const int u = it * 256 + tid;
            const int row = u >> 2, cc = u & 3;
            const unsigned dst = (unsigned)((it * 256 + w * 64) * 16);
            gload_lds16(A + (size_t)(bm + row) * DM + k0 + cc * 8, asA + dst);
            gload_lds16(B + (size_t)(bn + row) * DM + k0 + cc * 8, asB + dst);
        }
        __syncthreads();
        bf16x8v af[4], bf[4];
#pragma unroll
        for (int m = 0; m < 4; ++m)
            af[m] = *(const bf16x8v*)&As[(wr * 64 + m * 16 + a16) * 32 + g * 8];
#pragma unroll
        for (int n = 0; n < 4; ++n)
            bf[n] = *(const bf16x8v*)&Bs[(wc * 64 + n * 16 + a16) * 32 + g * 8];
#pragma unroll
        for (int m = 0; m < 4; ++m)
#pragma unroll
            for (int n = 0; n < 4; ++n)
                acc[m][n] = __builtin_amdgcn_mfma_f32_16x16x32_bf16(af[m], bf[n], acc[m][n], 0, 0, 0);
    }
#pragma unroll
    for (int m = 0; m < 4; ++m) {
        const int row0 = bm + wr * 64 + m * 16 + g * 4;
#pragma unroll
        for (int r = 0; r < 4; ++r) {
            const int row = row0 + r;
            const float wk = wts[(size_t)row * NPATH + path];
#pragma unroll
            for (int n = 0; n < 4; ++n) {
                const int col = bn + wc * 64 + n * 16 + a16;
                const float v = (acc[m][n][r] + bias[col]) * wk;
                const size_t oi = (size_t)row * DM + col;
                if (first) out[oi] = v; else out[oi] += v;
            }
        }
    }
}

// ---------------------------------------------------------------------------
// bf16 MFMA flash attention v8 (R10-proven): QBLK=128, no-max softmax,
// T14 register prefetch of next KV tile.
// ---------------------------------------------------------------------------
__global__ __launch_bounds__(256)
void attn_bf16(const __bf16* __restrict__ qkv, __bf16* __restrict__ O)
{
    __shared__ __attribute__((aligned(16))) __bf16 Ks[64 * 72];
    __shared__ __attribute__((aligned(16))) __bf16 Vt[64 * 72];
    __shared__ __attribute__((aligned(16))) __bf16 Pq[4][32 * 72];
    const int tid = threadIdx.x;
    const int l = tid & 63, w = tid >> 6;
    const int a = l & 15, g = l >> 4;
    const int bh = blockIdx.y;
    const int b = bh >> 3, h = bh & 7;
    const int qb = blockIdx.x << 7;
    const size_t base = (size_t)b * SEQ * TD;

    bf16x8v qA0, qA1, qB0, qB1;
    {
        const __bf16* qp = qkv + base + (size_t)(qb + w * 32 + a) * TD + h * 64 + g * 8;
        qA0 = *(const bf16x8v*)qp;
        qA1 = *(const bf16x8v*)(qp + 32);
        const __bf16* qp2 = qp + (size_t)16 * TD;
        qB0 = *(const bf16x8v*)qp2;
        qB1 = *(const bf16x8v*)(qp2 + 32);
    }
    float lA = 0.f, lB = 0.f;
    f32x4v oA[4] = {}, oB[4] = {};
    __bf16* pw = &Pq[w][0];
    const int sc8 = tid & 7;
    const int sr  = tid >> 3;
    const int vcol8 = (sr >> 2) ^ sc8;

    bf16x8v kpre0, kpre1, vpre0, vpre1;
    {
        const __bf16* kp0 = qkv + base + (size_t)sr * TD + DM + h * 64 + sc8 * 8;
        kpre0 = *(const bf16x8v*)kp0;
        kpre1 = *(const bf16x8v*)(kp0 + (size_t)32 * TD);
        const __bf16* vp0 = qkv + base + (size_t)(2 * sr) * TD + 2 * DM + h * 64 + sc8 * 8;
        vpre0 = *(const bf16x8v*)vp0;
        vpre1 = *(const bf16x8v*)(vp0 + TD);
    }

    for (int kt = 0; kt < SEQ; kt += 64) {
        __syncthreads();
        *(bf16x8v*)&Ks[sr * 72 + sc8 * 8] = kpre0;
        *(bf16x8v*)&Ks[(32 + sr) * 72 + sc8 * 8] = kpre1;
        {
            const u16x8 v0 = __builtin_bit_cast(u16x8, vpre0);
            const u16x8 v1 = __builtin_bit_cast(u16x8, vpre1);
#pragma unroll
            for (int j = 0; j < 8; ++j) {
                const unsigned pk = (unsigned)v0[j] | ((unsigned)v1[j] << 16);
                *(unsigned*)&Vt[(sc8 * 8 + j) * 72 + vcol8 * 8 + (sr & 3) * 2] = pk;
            }
        }
        if (kt + 64 < SEQ) {
            const __bf16* kp0 = qkv + base + (size_t)(kt + 64 + sr) * TD + DM + h * 64 + sc8 * 8;
            kpre0 = *(const bf16x8v*)kp0;
            kpre1 = *(const bf16x8v*)(kp0 + (size_t)32 * TD);
            const __bf16* vp0 = qkv + base + (size_t)(kt + 64 + 2 * sr) * TD + 2 * DM + h * 64 + sc8 * 8;
            vpre0 = *(const bf16x8v*)vp0;
            vpre1 = *(const bf16x8v*)(vp0 + TD);
        }
        __syncthreads();

        f32x4v sA[4] = {}, sB[4] = {};
        __builtin_amdgcn_s_setprio(1);
#pragma unroll
        for (int kc = 0; kc < 4; ++kc) {
            const bf16x8v kf0 = *(const bf16x8v*)&Ks[(kc * 16 + a) * 72 + g * 8];
            const bf16x8v kf1 = *(const bf16x8v*)&Ks[(kc * 16 + a) * 72 + 32 + g * 8];
            sA[kc] = __builtin_amdgcn_mfma_f32_16x16x32_bf16(kf0, qA0, sA[kc], 0, 0, 0);
            sA[kc] = __builtin_amdgcn_mfma_f32_16x16x32_bf16(kf1, qA1, sA[kc], 0, 0, 0);
            sB[kc] = __builtin_amdgcn_mfma_f32_16x16x32_bf16(kf0, qB0, sB[kc], 0, 0, 0);
            sB[kc] = __builtin_amdgcn_mfma_f32_16x16x32_bf16(kf1, qB1, sB[kc], 0, 0, 0);
        }
        __builtin_amdgcn_s_setprio(0);

        float lsumA = 0.f, lsumB = 0.f;
#pragma unroll
        for (int kc = 0; kc < 4; ++kc) {
            bf16x4v pkA, pkB;
#pragma unroll
            for (int r = 0; r < 4; ++r) {
                const float pA = __expf(sA[kc][r]);
                const float pB = __expf(sB[kc][r]);
                lsumA += pA; lsumB += pB;
                pkA[r] = (__bf16)pA; pkB[r] = (__bf16)pB;
            }
            *(bf16x4v*)&pw[a * 72 + kc * 16 + g * 4] = pkA;
            *(bf16x4v*)&pw[(16 + a) * 72 + kc * 16 + g * 4] = pkB;
        }
        lsumA += __shfl_xor(lsumA, 16);
        lsumA += __shfl_xor(lsumA, 32);
        lsumB += __shfl_xor(lsumB, 16);
        lsumB += __shfl_xor(lsumB, 32);
        lA += lsumA; lB += lsumB;
        asm volatile("s_waitcnt lgkmcnt(0)" ::: "memory");

        __builtin_amdgcn_s_setprio(1);
#pragma unroll
        for (int dc = 0; dc < 4; ++dc) {
            const int vrow = dc * 16 + a;
#pragma unroll
            for (int kh = 0; kh < 2; ++kh) {
                const bf16x8v vf = *(const bf16x8v*)&Vt[vrow * 72 + ((((kh << 2) + g) ^ ((vrow >> 3) & 7)) & 7) * 8];
                const bf16x8v paA = *(const bf16x8v*)&pw[a * 72 + kh * 32 + g * 8];
                const bf16x8v paB = *(const bf16x8v*)&pw[(16 + a) * 72 + kh * 32 + g * 8];
                oA[dc] = __builtin_amdgcn_mfma_f32_16x16x32_bf16(paA, vf, oA[dc], 0, 0, 0);
                oB[dc] = __builtin_amdgcn_mfma_f32_16x16x32_bf16(paB, vf, oB[dc], 0, 0, 0);
            }
        }
        __builtin_amdgcn_s_setprio(0);
    }

    float liA[4], liB[4];
#pragma unroll
    for (int r = 0; r < 4; ++r) {
        liA[r] = 1.f / __shfl(lA, 4 * g + r);
        liB[r] = 1.f / __shfl(lB, 4 * g + r);
    }
    const int row0 = qb + w * 32 + g * 4;
#pragma unroll
    for (int dc = 0; dc < 4; ++dc)
#pragma unroll
        for (int r = 0; r < 4; ++r) {
            O[(size_t)(b * SEQ + row0 + r) * DM + h * 64 + dc * 16 + a] = (__bf16)(oA[dc][r] * liA[r]);
            O[(size_t)(b * SEQ + row0 + 16 + r) * DM + h * 64 + dc * 16 + a] = (__bf16)(oB[dc][r] * liB[r]);
        }
}

// ---------------------------------------------------------------------------
extern "C" void kernel_launch(void* const* d_in, const int* in_sizes, int n_in,
                              void* d_out, int out_size, void* d_ws, size_t ws_size,
                              hipStream_t stream)
{
    const float* x         = (const float*)d_in[0];
    const float* ctx_in_w  = (const float*)d_in[1];
    const float* ctx_in_b  = (const float*)d_in[2];
    const float* ctx_out_w = (const float*)d_in[3];
    const float* ctx_out_b = (const float*)d_in[4];
    const float* r_w1      = (const float*)d_in[5];
    const float* r_b1      = (const float*)d_in[6];
    const float* r_w2      = (const float*)d_in[7];
    const float* r_b2      = (const float*)d_in[8];
    const float* r_w3      = (const float*)d_in[9];
    const float* r_b3      = (const float*)d_in[10];
    const float* p_in_w    = (const float*)d_in[11];
    const float* p_in_b    = (const float*)d_in[12];
    const float* p_out_w   = (const float*)d_in[13];
    const float* p_out_b   = (const float*)d_in[14];

    float* out  = (float*)d_out;
    float* loss = out + (size_t)TOKENS * DM;
    float* wts  = loss + 1;

    float* F = (float*)d_ws;
    float* qkvbuf   = F;                            // 12,582,912 f32 (router)
    float* obuf     = F + 12582912;                 //  4,194,304 f32 (router)
    float* attended = F;                            // overlays (router only)
    float* h1       = F + 4194304;
    float* h2       = F + 5242880;
    float* scores   = F + 5767168;
    float* freq     = F + 5898240;

    const int M = TOKENS;
    dim3 blk(256);
    const bool big = ws_size >= (size_t)134217728;  // 128 MB

    // ---- Router (fp32-exact) ----
    hipMemsetAsync(freq, 0, NPATH * sizeof(float), stream);
    gemm_f32_nt<0><<<dim3(TD / 128, M / 128), blk, 0, stream>>>(
        x, ctx_in_w, ctx_in_b, qkvbuf, M, TD, DM, DM, DM, TD, 1.f, 0, 0);
    if (big) {
        float* Sbuf = F + 16777216;                 // 64 MB
        gemm_f32_nt<1><<<dim3(8, 8, 16), blk, 0, stream>>>(
            qkvbuf, qkvbuf, nullptr, Sbuf, SEQ, SEQ, 256, TD, TD, SEQ, 0.0625f, 0, 1);
        softmax_rows<<<dim3(16 * SEQ / 4), blk, 0, stream>>>(Sbuf);
        gemm_f32_pv<<<dim3(2, 8, 16), blk, 0, stream>>>(Sbuf, qkvbuf, obuf);
    } else {
        flash_attn<256><<<dim3(SEQ / 32, 8 * 2), blk, 0, stream>>>(qkvbuf, obuf, 2, 1.f / 16.f);
    }
    gemm_f32_nt<1><<<dim3(DM / 128, M / 128), blk, 0, stream>>>(
        obuf, ctx_out_w, ctx_out_b, attended, M, DM, DM, DM, DM, DM, 1.f, 0, 0);
    gemm_f32_nt<1><<<dim3(1, M / 128), blk, 0, stream>>>(
        attended, r_w1, r_b1, h1, M, 128, DM, DM, DM, 128, 1.f, 1, 0);
    gemm_f32<<<dim3(1, M / 64), blk, 0, stream>>>(h1, r_w2, r_b2, h2, M, 64, 128, 1);
    gemm_f32<<<dim3(1, M / 64), blk, 0, stream>>>(h2, r_w3, r_b3, scores, M, NPATH, 64, 0);
    router_epilogue<<<dim3(TOKENS / 256), blk, 0, stream>>>(scores, freq, wts);
    glbl_loss_kernel<<<dim3(1), dim3(64), 0, stream>>>(freq, loss);

    // ---- Pathways (bf16 MFMA) ----
    if (big) {
        __bf16* xb       = (__bf16*)F;
        __bf16* qkv_b    = (__bf16*)(F + 2097152);
        __bf16* obuf_b   = (__bf16*)(F + 8388608);
        __bf16* wqkv_all = (__bf16*)(F + 16777216);
        __bf16* wout_all = (__bf16*)(F + 23068672);
        cast_f32_bf16<<<dim3(TOKENS * DM / 4 / 256), blk, 0, stream>>>(x, xb, TOKENS * DM);
        cast_f32_bf16<<<dim3(NPATH * TD * DM / 4 / 256), blk, 0, stream>>>(
            p_in_w, wqkv_all, NPATH * TD * DM);
        cast_f32_bf16<<<dim3(NPATH * DM * DM / 4 / 256), blk, 0, stream>>>(
            p_out_w, wout_all, NPATH * DM * DM);
        for (int p = 0; p < NPATH; ++p) {
            gemm_bf16_qkv<<<dim3(TD / 128, M / 128), blk, 0, stream>>>(
                xb, wqkv_all + (size_t)p * TD * DM, p_in_b + (size_t)p * TD, qkv_b, TD, DM);
            attn_bf16<<<dim3(SEQ / 128, 64), blk, 0, stream>>>(qkv_b, obuf_b);
            gemm_bf16_out<<<dim3(DM / 128, M / 128), blk, 0, stream>>>(
                obuf_b, wout_all + (size_t)p * DM * DM, p_out_b + (size_t)p * DM, wts, out, p, p == 0);
        }
    } else {
        __bf16* xb     = (__bf16*)F;
        __bf16* qkv_b  = (__bf16*)(F + 2097152);
        __bf16* obuf_b = (__bf16*)(F + 8388608);
        __bf16* wqkv_b = (__bf16*)(F + 12582912);
        __bf16* wout_b = (__bf16*)(F + 12976128);
        cast_f32_bf16<<<dim3(TOKENS * DM / 4 / 256), blk, 0, stream>>>(x, xb, TOKENS * DM);
        for (int p = 0; p < NPATH; ++p) {
            cast_f32_bf16<<<dim3(TD * DM / 4 / 256), blk, 0, stream>>>(
                p_in_w + (size_t)p * TD * DM, wqkv_b, TD * DM);
            cast_f32_bf16<<<dim3(DM * DM / 4 / 256), blk, 0, stream>>>(
                p_out_w + (size_t)p * DM * DM, wout_b, DM * DM);
            gemm_bf16_qkv<<<dim3(TD / 128, M / 128), blk, 0, stream>>>(
                xb, wqkv_b, p_in_b + (size_t)p * TD, qkv_b, TD, DM);
            attn_bf16<<<dim3(SEQ / 128, 64), blk, 0, stream>>>(qkv_b, obuf_b);
            gemm_bf16_out<<<dim3(DM / 128, M / 128), blk, 0, stream>>>(
                obuf_b, wout_b, p_out_b + (size_t)p * DM, wts, out, p, p == 0);
        }
    }
}

// Round 16
// 1922.788 us; speedup vs baseline: 1.0846x; 1.0846x over previous
//
#include <hip/hip_runtime.h>
#include <math.h>

#define TOKENS 8192
#define DM 512
#define TD 1536
#define SEQ 1024
#define NPATH 16
#define TOPK 8

typedef __bf16 bf16x8v __attribute__((ext_vector_type(8)));
typedef __bf16 bf16x4v __attribute__((ext_vector_type(4)));
typedef float f32x4v __attribute__((ext_vector_type(4)));
typedef unsigned short u16x8 __attribute__((ext_vector_type(8)));

__device__ __forceinline__ void gload_lds16(const void* gp, unsigned lds_byte_off) {
    __builtin_amdgcn_global_load_lds(
        (const __attribute__((address_space(1))) unsigned int*)(uintptr_t)gp,
        (__attribute__((address_space(3))) unsigned int*)(uintptr_t)lds_byte_off,
        16, 0, 0);
}

// ---------------------------------------------------------------------------
// fp32 NT GEMM (R15-proven): PREF=1 register dbuf for latency-exposed
// dispatches; PREF=0 plain. zmode=1: batched router QK^T.
// ---------------------------------------------------------------------------
template <int PREF>
__global__ __launch_bounds__(256)
void gemm_f32_nt(const float* __restrict__ A, const float* __restrict__ B,
                 const float* __restrict__ bias, float* __restrict__ C,
                 int M, int N, int K, int lda, int ldb, int ldc,
                 float alpha, int relu, int zmode)
{
    __shared__ float As[16][132];
    __shared__ float Bs[16][132];
    if (zmode == 1) {
        const int z = blockIdx.z, bb = z >> 1, hh = z & 1;
        A += (size_t)bb * SEQ * TD + hh * 256;
        B += (size_t)bb * SEQ * TD + 512 + hh * 256;
        C += (size_t)z * SEQ * SEQ;
    }
    const int tid = threadIdx.x;
    const int bm = blockIdx.y << 7, bn = blockIdx.x << 7;
    const int tx4 = (tid & 15) << 2, ty4 = ((tid >> 4) & 15) << 2;
    float acc[8][8] = {};

    if constexpr (PREF) {
        const int srow = tid >> 2, skc4 = (tid & 3) << 2;
        const float* Ap = A + (size_t)(bm + srow) * lda + skc4;
        const float* Ap2 = A + (size_t)(bm + 64 + srow) * lda + skc4;
        const float* Bp = B + (size_t)(bn + srow) * ldb + skc4;
        const float* Bp2 = B + (size_t)(bn + 64 + srow) * ldb + skc4;
        float4 pa0 = *(const float4*)Ap,  pa1 = *(const float4*)Ap2;
        float4 pb0 = *(const float4*)Bp,  pb1 = *(const float4*)Bp2;
        for (int k0 = 0; k0 < K; k0 += 16) {
            __syncthreads();
            As[skc4 + 0][srow] = pa0.x; As[skc4 + 1][srow] = pa0.y;
            As[skc4 + 2][srow] = pa0.z; As[skc4 + 3][srow] = pa0.w;
            As[skc4 + 0][64 + srow] = pa1.x; As[skc4 + 1][64 + srow] = pa1.y;
            As[skc4 + 2][64 + srow] = pa1.z; As[skc4 + 3][64 + srow] = pa1.w;
            Bs[skc4 + 0][srow] = pb0.x; Bs[skc4 + 1][srow] = pb0.y;
            Bs[skc4 + 2][srow] = pb0.z; Bs[skc4 + 3][srow] = pb0.w;
            Bs[skc4 + 0][64 + srow] = pb1.x; Bs[skc4 + 1][64 + srow] = pb1.y;
            Bs[skc4 + 2][64 + srow] = pb1.z; Bs[skc4 + 3][64 + srow] = pb1.w;
            if (k0 + 16 < K) {
                pa0 = *(const float4*)(Ap + k0 + 16);
                pa1 = *(const float4*)(Ap2 + k0 + 16);
                pb0 = *(const float4*)(Bp + k0 + 16);
                pb1 = *(const float4*)(Bp2 + k0 + 16);
            }
            __syncthreads();
#pragma unroll
            for (int kk = 0; kk < 16; ++kk) {
                const float4 a0 = *(const float4*)&As[kk][ty4];
                const float4 a1 = *(const float4*)&As[kk][64 + ty4];
                const float4 b0 = *(const float4*)&Bs[kk][tx4];
                const float4 b1 = *(const float4*)&Bs[kk][64 + tx4];
                const float aa[8] = {a0.x, a0.y, a0.z, a0.w, a1.x, a1.y, a1.z, a1.w};
                const float bb[8] = {b0.x, b0.y, b0.z, b0.w, b1.x, b1.y, b1.z, b1.w};
#pragma unroll
                for (int i = 0; i < 8; ++i)
#pragma unroll
                    for (int j = 0; j < 8; ++j)
                        acc[i][j] = fmaf(aa[i], bb[j], acc[i][j]);
            }
        }
    } else {
        for (int k0 = 0; k0 < K; k0 += 16) {
            __syncthreads();
#pragma unroll
            for (int it = 0; it < 2; ++it) {
                const int u = (it << 8) + tid;
                const int row = u >> 2, kc4 = (u & 3) << 2;
                const float4 av = *(const float4*)(A + (size_t)(bm + row) * lda + k0 + kc4);
                As[kc4 + 0][row] = av.x; As[kc4 + 1][row] = av.y;
                As[kc4 + 2][row] = av.z; As[kc4 + 3][row] = av.w;
                const float4 bv = *(const float4*)(B + (size_t)(bn + row) * ldb + k0 + kc4);
                Bs[kc4 + 0][row] = bv.x; Bs[kc4 + 1][row] = bv.y;
                Bs[kc4 + 2][row] = bv.z; Bs[kc4 + 3][row] = bv.w;
            }
            __syncthreads();
#pragma unroll
            for (int kk = 0; kk < 16; ++kk) {
                const float4 a0 = *(const float4*)&As[kk][ty4];
                const float4 a1 = *(const float4*)&As[kk][64 + ty4];
                const float4 b0 = *(const float4*)&Bs[kk][tx4];
                const float4 b1 = *(const float4*)&Bs[kk][64 + tx4];
                const float aa[8] = {a0.x, a0.y, a0.z, a0.w, a1.x, a1.y, a1.z, a1.w};
                const float bb[8] = {b0.x, b0.y, b0.z, b0.w, b1.x, b1.y, b1.z, b1.w};
#pragma unroll
                for (int i = 0; i < 8; ++i)
#pragma unroll
                    for (int j = 0; j < 8; ++j)
                        acc[i][j] = fmaf(aa[i], bb[j], acc[i][j]);
            }
        }
    }

    float bcol[8] = {};
    if (bias) {
        const float4 bL = *(const float4*)(bias + bn + tx4);
        const float4 bH = *(const float4*)(bias + bn + 64 + tx4);
        bcol[0] = bL.x; bcol[1] = bL.y; bcol[2] = bL.z; bcol[3] = bL.w;
        bcol[4] = bH.x; bcol[5] = bH.y; bcol[6] = bH.z; bcol[7] = bH.w;
    }
#pragma unroll
    for (int i = 0; i < 8; ++i) {
        const int row = bm + ((i < 4) ? (ty4 + i) : (64 + ty4 + i - 4));
        float* cp = C + (size_t)row * ldc + bn;
        float v[8];
#pragma unroll
        for (int j = 0; j < 8; ++j) {
            v[j] = alpha * acc[i][j] + bcol[j];
            if (relu) v[j] = fmaxf(v[j], 0.f);
        }
        *(float4*)(cp + tx4) = make_float4(v[0], v[1], v[2], v[3]);
        *(float4*)(cp + 64 + tx4) = make_float4(v[4], v[5], v[6], v[7]);
    }
}

// ---------------------------------------------------------------------------
// fp32 NN GEMM (router PV), batched z; register prefetch.
// ---------------------------------------------------------------------------
__global__ __launch_bounds__(256)
void gemm_f32_pv(const float* __restrict__ Sb, const float* __restrict__ qkv,
                 float* __restrict__ obuf)
{
    __shared__ float As[16][132];
    __shared__ float Bs[16][128];
    const int z = blockIdx.z, bb = z >> 1, hh = z & 1;
    const float* A = Sb + (size_t)z * SEQ * SEQ;
    const float* B = qkv + (size_t)bb * SEQ * TD + 1024 + hh * 256;
    float* C = obuf + (size_t)bb * SEQ * 512 + hh * 256;
    const int tid = threadIdx.x;
    const int bm = blockIdx.y << 7, bn = blockIdx.x << 7;
    const int tx4 = (tid & 15) << 2, ty4 = ((tid >> 4) & 15) << 2;
    const int ar = tid >> 2, ak4 = (tid & 3) << 2;
    const int br = tid >> 5, bn4 = (tid & 31) << 2;
    const float* ApA  = A + (size_t)(bm + ar) * SEQ + ak4;
    const float* ApA2 = A + (size_t)(bm + 64 + ar) * SEQ + ak4;
    const float* BpB  = B + (size_t)br * TD + bn + bn4;
    const float* BpB2 = B + (size_t)(8 + br) * TD + bn + bn4;

    float4 a0 = *(const float4*)ApA, a1 = *(const float4*)ApA2;
    float4 b0 = *(const float4*)BpB, b1 = *(const float4*)BpB2;

    float acc[8][8] = {};
    for (int k0 = 0; k0 < SEQ; k0 += 16) {
        __syncthreads();
        As[ak4 + 0][ar] = a0.x; As[ak4 + 1][ar] = a0.y;
        As[ak4 + 2][ar] = a0.z; As[ak4 + 3][ar] = a0.w;
        As[ak4 + 0][64 + ar] = a1.x; As[ak4 + 1][64 + ar] = a1.y;
        As[ak4 + 2][64 + ar] = a1.z; As[ak4 + 3][64 + ar] = a1.w;
        *(float4*)&Bs[br][bn4] = b0;
        *(float4*)&Bs[8 + br][bn4] = b1;
        if (k0 + 16 < SEQ) {
            a0 = *(const float4*)(ApA + k0 + 16);
            a1 = *(const float4*)(ApA2 + k0 + 16);
            b0 = *(const float4*)(BpB + (size_t)(k0 + 16) * TD);
            b1 = *(const float4*)(BpB2 + (size_t)(k0 + 16) * TD);
        }
        __syncthreads();
#pragma unroll
        for (int kk = 0; kk < 16; ++kk) {
            const float4 A0 = *(const float4*)&As[kk][ty4];
            const float4 A1 = *(const float4*)&As[kk][64 + ty4];
            const float4 B0 = *(const float4*)&Bs[kk][tx4];
            const float4 B1 = *(const float4*)&Bs[kk][64 + tx4];
            const float aa[8] = {A0.x, A0.y, A0.z, A0.w, A1.x, A1.y, A1.z, A1.w};
            const float bb[8] = {B0.x, B0.y, B0.z, B0.w, B1.x, B1.y, B1.z, B1.w};
#pragma unroll
            for (int i = 0; i < 8; ++i)
#pragma unroll
                for (int j = 0; j < 8; ++j)
                    acc[i][j] = fmaf(aa[i], bb[j], acc[i][j]);
        }
    }
#pragma unroll
    for (int i = 0; i < 8; ++i) {
        const int row = bm + ((i < 4) ? (ty4 + i) : (64 + ty4 + i - 4));
        float* cp = C + (size_t)row * 512 + bn;
        *(float4*)(cp + tx4) = make_float4(acc[i][0], acc[i][1], acc[i][2], acc[i][3]);
        *(float4*)(cp + 64 + tx4) = make_float4(acc[i][4], acc[i][5], acc[i][6], acc[i][7]);
    }
}

// Row softmax over 1024 cols, in-place. One wave per row.
__global__ __launch_bounds__(256)
void softmax_rows(float* __restrict__ S_)
{
    const int row = blockIdx.x * 4 + (threadIdx.x >> 6);
    const int lane = threadIdx.x & 63;
    float* rp = S_ + (size_t)row * 1024 + lane * 16;
    float4 v[4];
#pragma unroll
    for (int i = 0; i < 4; ++i) v[i] = *(const float4*)(rp + i * 4);
    float mx = -INFINITY;
#pragma unroll
    for (int i = 0; i < 4; ++i)
        mx = fmaxf(mx, fmaxf(fmaxf(v[i].x, v[i].y), fmaxf(v[i].z, v[i].w)));
#pragma unroll
    for (int off = 1; off < 64; off <<= 1) mx = fmaxf(mx, __shfl_xor(mx, off));
    float sum = 0.f;
#pragma unroll
    for (int i = 0; i < 4; ++i) {
        v[i].x = __expf(v[i].x - mx); v[i].y = __expf(v[i].y - mx);
        v[i].z = __expf(v[i].z - mx); v[i].w = __expf(v[i].w - mx);
        sum += v[i].x + v[i].y + v[i].z + v[i].w;
    }
#pragma unroll
    for (int off = 1; off < 64; off <<= 1) sum += __shfl_xor(sum, off);
    const float inv = 1.f / sum;
#pragma unroll
    for (int i = 0; i < 4; ++i) {
        v[i].x *= inv; v[i].y *= inv; v[i].z *= inv; v[i].w *= inv;
        *(float4*)(rp + i * 4) = v[i];
    }
}

// ---------------------------------------------------------------------------
// fp32 GEMM 64x64 (small router layers r_w2/r_w3).
// ---------------------------------------------------------------------------
__global__ __launch_bounds__(256)
void gemm_f32(const float* __restrict__ A, const float* __restrict__ W,
              const float* __restrict__ bias, float* __restrict__ C,
              int M, int N, int K, int relu)
{
    __shared__ float As[16][64];
    __shared__ float Bs[16][64];
    const int bm = blockIdx.y << 6;
    const int bn = blockIdx.x << 6;
    const int tid = threadIdx.x;
    const int tx = tid & 15, ty = tid >> 4;
    const int lr = tid >> 2;
    const int lc = (tid & 3) << 2;
    float acc[4][4] = {};
    for (int k0 = 0; k0 < K; k0 += 16) {
        float4 av = *(const float4*)(A + (size_t)(bm + lr) * K + (k0 + lc));
        float4 bv = make_float4(0.f, 0.f, 0.f, 0.f);
        const int wr = bn + lr;
        if (wr < N) bv = *(const float4*)(W + (size_t)wr * K + (k0 + lc));
        __syncthreads();
        As[lc + 0][lr] = av.x; As[lc + 1][lr] = av.y;
        As[lc + 2][lr] = av.z; As[lc + 3][lr] = av.w;
        Bs[lc + 0][lr] = bv.x; Bs[lc + 1][lr] = bv.y;
        Bs[lc + 2][lr] = bv.z; Bs[lc + 3][lr] = bv.w;
        __syncthreads();
#pragma unroll
        for (int kk = 0; kk < 16; ++kk) {
            const float4 a4 = *(const float4*)(&As[kk][ty << 2]);
            const float4 b4 = *(const float4*)(&Bs[kk][tx << 2]);
            const float a[4] = {a4.x, a4.y, a4.z, a4.w};
            const float b[4] = {b4.x, b4.y, b4.z, b4.w};
#pragma unroll
            for (int i = 0; i < 4; ++i)
#pragma unroll
                for (int j = 0; j < 4; ++j)
                    acc[i][j] = fmaf(a[i], b[j], acc[i][j]);
        }
    }
#pragma unroll
    for (int i = 0; i < 4; ++i) {
        const int m = bm + (ty << 2) + i;
#pragma unroll
        for (int j = 0; j < 4; ++j) {
            const int n = bn + (tx << 2) + j;
            if (n < N) {
                float v = acc[i][j] + bias[n];
                if (relu) v = fmaxf(v, 0.f);
                C[(size_t)m * N + n] = v;
            }
        }
    }
}

// ---------------------------------------------------------------------------
// fp32 flash attention fallback (router ctx, DH=256) — used when ws is small.
// ---------------------------------------------------------------------------
template <int DH>
__global__ __launch_bounds__(256)
void flash_attn(const float* __restrict__ qkv, float* __restrict__ O,
                int H, float scale)
{
    constexpr int NU = DH / 64;
    __shared__ float Qs[32][DH + 4];
    __shared__ float Ks[32][DH + 4];
    __shared__ float Vs[32][DH + 4];
    __shared__ float Ps[32][33];
    const int tid = threadIdx.x;
    const int g2 = tid & 15;
    const int rs = tid >> 4;
    const int bh = blockIdx.y;
    const int b = bh / H, h = bh - b * H;
    const int rb = blockIdx.x << 5;
    const float* qb = qkv + (size_t)b * SEQ * TD + (size_t)h * DH;
    const float* kb = qb + DM;
    const float* vb = qb + 2 * DM;

    for (int idx = tid; idx < 32 * (DH / 4); idx += 256) {
        const int rr = idx / (DH / 4);
        const int dp = (idx - rr * (DH / 4)) << 2;
        float4 v = *(const float4*)(qb + (size_t)(rb + rr) * TD + dp);
        v.x *= scale; v.y *= scale; v.z *= scale; v.w *= scale;
        *(float4*)&Qs[rr][dp] = v;
    }
    float m0 = -INFINITY, m1 = -INFINITY, l0 = 0.f, l1 = 0.f;
    float4 o0[NU], o1[NU];
#pragma unroll
    for (int u = 0; u < NU; ++u) {
        o0[u] = make_float4(0.f, 0.f, 0.f, 0.f);
        o1[u] = make_float4(0.f, 0.f, 0.f, 0.f);
    }
    __syncthreads();

    for (int kt = 0; kt < SEQ; kt += 32) {
        for (int idx = tid; idx < 32 * (DH / 4); idx += 256) {
            const int rr = idx / (DH / 4);
            const int dp = (idx - rr * (DH / 4)) << 2;
            *(float4*)&Ks[rr][dp] = *(const float4*)(kb + (size_t)(kt + rr) * TD + dp);
            *(float4*)&Vs[rr][dp] = *(const float4*)(vb + (size_t)(kt + rr) * TD + dp);
        }
        __syncthreads();
        float s00 = 0.f, s01 = 0.f, s10 = 0.f, s11 = 0.f;
        const int cA = g2, cB = g2 + 16;
#pragma unroll 8
        for (int i = 0; i < DH; i += 4) {
            const float4 q0 = *(const float4*)&Qs[rs][i];
            const float4 q1 = *(const float4*)&Qs[rs + 16][i];
            const float4 k0 = *(const float4*)&Ks[cA][i];
            const float4 k1 = *(const float4*)&Ks[cB][i];
            s00 += q0.x * k0.x + q0.y * k0.y + q0.z * k0.z + q0.w * k0.w;
            s01 += q0.x * k1.x + q0.y * k1.y + q0.z * k1.z + q0.w * k1.w;
            s10 += q1.x * k0.x + q1.y * k0.y + q1.z * k0.z + q1.w * k0.w;
            s11 += q1.x * k1.x + q1.y * k1.y + q1.z * k1.z + q1.w * k1.w;
        }
        float ml0 = fmaxf(s00, s01), ml1 = fmaxf(s10, s11);
#pragma unroll
        for (int off = 1; off < 16; off <<= 1) {
            ml0 = fmaxf(ml0, __shfl_xor(ml0, off));
            ml1 = fmaxf(ml1, __shfl_xor(ml1, off));
        }
        const float n0 = fmaxf(m0, ml0), n1 = fmaxf(m1, ml1);
        const float f0 = __expf(m0 - n0), f1 = __expf(m1 - n1);
        const float p00 = __expf(s00 - n0), p01 = __expf(s01 - n0);
        const float p10 = __expf(s10 - n1), p11 = __expf(s11 - n1);
        float sum0 = p00 + p01, sum1 = p10 + p11;
#pragma unroll
        for (int off = 1; off < 16; off <<= 1) {
            sum0 += __shfl_xor(sum0, off);
            sum1 += __shfl_xor(sum1, off);
        }
        l0 = l0 * f0 + sum0; l1 = l1 * f1 + sum1;
        m0 = n0; m1 = n1;
#pragma unroll
        for (int u = 0; u < NU; ++u) {
            o0[u].x *= f0; o0[u].y *= f0; o0[u].z *= f0; o0[u].w *= f0;
            o1[u].x *= f1; o1[u].y *= f1; o1[u].z *= f1; o1[u].w *= f1;
        }
        Ps[rs][cA] = p00; Ps[rs][cB] = p01;
        Ps[rs + 16][cA] = p10; Ps[rs + 16][cB] = p11;
        __syncthreads();
#pragma unroll 4
        for (int c = 0; c < 32; ++c) {
            const float pv0 = Ps[rs][c];
            const float pv1 = Ps[rs + 16][c];
#pragma unroll
            for (int u = 0; u < NU; ++u) {
                const float4 v4 = *(const float4*)&Vs[c][(g2 << 2) + (u << 6)];
                o0[u].x = fmaf(pv0, v4.x, o0[u].x);
                o0[u].y = fmaf(pv0, v4.y, o0[u].y);
                o0[u].z = fmaf(pv0, v4.z, o0[u].z);
                o0[u].w = fmaf(pv0, v4.w, o0[u].w);
                o1[u].x = fmaf(pv1, v4.x, o1[u].x);
                o1[u].y = fmaf(pv1, v4.y, o1[u].y);
                o1[u].z = fmaf(pv1, v4.z, o1[u].z);
                o1[u].w = fmaf(pv1, v4.w, o1[u].w);
            }
        }
        __syncthreads();
    }
    const float i0 = 1.f / l0, i1 = 1.f / l1;
    float* ob0 = O + (size_t)b * SEQ * DM + (size_t)(rb + rs) * DM + h * DH;
    float* ob1 = ob0 + (size_t)16 * DM;
#pragma unroll
    for (int u = 0; u < NU; ++u) {
        float4 w0 = o0[u];
        w0.x *= i0; w0.y *= i0; w0.z *= i0; w0.w *= i0;
        *(float4*)(ob0 + (g2 << 2) + (u << 6)) = w0;
        float4 w1 = o1[u];
        w1.x *= i1; w1.y *= i1; w1.z *= i1; w1.w *= i1;
        *(float4*)(ob1 + (g2 << 2) + (u << 6)) = w1;
    }
}

// ---------------------------------------------------------------------------
// Router epilogue + loss (fp32-exact)
// ---------------------------------------------------------------------------
__global__ __launch_bounds__(256)
void router_epilogue(const float* __restrict__ scores, float* __restrict__ freq,
                     float* __restrict__ weights)
{
    const int t = blockIdx.x * 256 + threadIdx.x;
    float s[NPATH];
#pragma unroll
    for (int i = 0; i < NPATH; ++i) s[i] = scores[(size_t)t * NPATH + i];
    float mx = s[0];
#pragma unroll
    for (int i = 1; i < NPATH; ++i) mx = fmaxf(mx, s[i]);
    float p[NPATH];
    float sum = 0.f;
#pragma unroll
    for (int i = 0; i < NPATH; ++i) { p[i] = expf(s[i] - mx); sum += p[i]; }
    const float inv = 1.f / sum;
#pragma unroll
    for (int i = 0; i < NPATH; ++i) p[i] *= inv;
#pragma unroll
    for (int i = 0; i < NPATH; ++i) {
        float v = p[i];
        for (int off = 32; off >= 1; off >>= 1) v += __shfl_xor(v, off);
        if ((threadIdx.x & 63) == 0) atomicAdd(&freq[i], v);
    }
    unsigned used = 0u;
    float topv[TOPK];
    int topi[TOPK];
    float wsum = 0.f;
#pragma unroll
    for (int k = 0; k < TOPK; ++k) {
        float best = -1.f; int bi = 0;
#pragma unroll
        for (int i = 0; i < NPATH; ++i) {
            if (!((used >> i) & 1u) && p[i] > best) { best = p[i]; bi = i; }
        }
        used |= 1u << bi;
        topv[k] = best; topi[k] = bi;
        wsum += best;
    }
    const float winv = 1.f / (wsum + 1e-8f);
    float w[NPATH];
#pragma unroll
    for (int i = 0; i < NPATH; ++i) w[i] = 0.f;
#pragma unroll
    for (int k = 0; k < TOPK; ++k) w[topi[k]] = topv[k] * winv;
#pragma unroll
    for (int i = 0; i < NPATH; ++i) weights[(size_t)t * NPATH + i] = w[i];
}

__global__ void glbl_loss_kernel(const float* __restrict__ freq, float* __restrict__ out)
{
    if (threadIdx.x == 0 && blockIdx.x == 0) {
        float acc = 0.f;
        for (int i = 0; i < NPATH; ++i) {
            const float f = freq[i] * (1.f / (float)TOKENS);
            acc += f * f;
        }
        out[0] = (float)NPATH * acc;
    }
}

__global__ __launch_bounds__(256)
void cast_f32_bf16(const float* __restrict__ src, __bf16* __restrict__ dst, int n)
{
    const int i = (blockIdx.x * 256 + threadIdx.x) * 4;
    if (i < n) {
        const float4 v = *(const float4*)(src + i);
        bf16x4v o;
        o[0] = (__bf16)v.x; o[1] = (__bf16)v.y; o[2] = (__bf16)v.z; o[3] = (__bf16)v.w;
        *(bf16x4v*)(dst + i) = o;
    }
}

// ===========================================================================
// Pathway role bodies (shared by standalone kernels and the fused dispatcher)
// ===========================================================================

// bf16 MFMA GEMM: C = A@B^T + bias; cols<512 (Q) scaled x0.125.
__device__ __forceinline__ void qkv_body(
    const __bf16* __restrict__ A, const __bf16* __restrict__ B,
    const float* __restrict__ bias, __bf16* __restrict__ C,
    int N, int K, int bx, int by, char* smem)
{
    __bf16* As = (__bf16*)smem;
    __bf16* Bs = (__bf16*)(smem + 8192);
    const int tid = threadIdx.x;
    const int l = tid & 63, w = tid >> 6;
    const int wr = w >> 1, wc = w & 1;
    const int a16 = l & 15, g = l >> 4;
    const int bm = by << 7, bn = bx << 7;
    const unsigned asA = (unsigned)(uintptr_t)(void*)As;
    const unsigned asB = (unsigned)(uintptr_t)(void*)Bs;

    f32x4v acc[4][4] = {};
    for (int k0 = 0; k0 < K; k0 += 32) {
        __syncthreads();
#pragma unroll
        for (int it = 0; it < 2; ++it) {
            const int u = it * 256 + tid;
            const int row = u >> 2, cc = u & 3;
            const unsigned dst = (unsigned)((it * 256 + w * 64) * 16);
            gload_lds16(A + (size_t)(bm + row) * K + k0 + cc * 8, asA + dst);
            gload_lds16(B + (size_t)(bn + row) * K + k0 + cc * 8, asB + dst);
        }
        __syncthreads();
        bf16x8v af[4], bf[4];
#pragma unroll
        for (int m = 0; m < 4; ++m)
            af[m] = *(const bf16x8v*)&As[(wr * 64 + m * 16 + a16) * 32 + g * 8];
#pragma unroll
        for (int n = 0; n < 4; ++n)
            bf[n] = *(const bf16x8v*)&Bs[(wc * 64 + n * 16 + a16) * 32 + g * 8];
#pragma unroll
        for (int m = 0; m < 4; ++m)
#pragma unroll
            for (int n = 0; n < 4; ++n)
                acc[m][n] = __builtin_amdgcn_mfma_f32_16x16x32_bf16(af[m], bf[n], acc[m][n], 0, 0, 0);
    }
#pragma unroll
    for (int n = 0; n < 4; ++n) {
        const int col = bn + wc * 64 + n * 16 + a16;
        const float bv = bias[col];
        const float sc = (col < DM) ? 0.125f : 1.0f;   // fold 1/sqrt(64) into Q
#pragma unroll
        for (int m = 0; m < 4; ++m) {
            const int row0 = bm + wr * 64 + m * 16 + g * 4;
#pragma unroll
            for (int r = 0; r < 4; ++r)
                C[(size_t)(row0 + r) * N + col] = (__bf16)((acc[m][n][r] + bv) * sc);
        }
    }
}

// Out-projection + weighted accumulate into fp32 out.
__device__ __forceinline__ void out_body(
    const __bf16* __restrict__ A, const __bf16* __restrict__ B,
    const float* __restrict__ bias, const float* __restrict__ wts,
    float* __restrict__ out, int path, int first, int bx, int by, char* smem)
{
    __bf16* As = (__bf16*)smem;
    __bf16* Bs = (__bf16*)(smem + 8192);
    const int tid = threadIdx.x;
    const int l = tid & 63, w = tid >> 6;
    const int wr = w >> 1, wc = w & 1;
    const int a16 = l & 15, g = l >> 4;
    const int bm = by << 7, bn = bx << 7;
    const unsigned asA = (unsigned)(uintptr_t)(void*)As;
    const unsigned asB = (unsigned)(uintptr_t)(void*)Bs;

    f32x4v acc[4][4] = {};
    for (int k0 = 0; k0 < DM; k0 += 32) {
        __syncthreads();
#pragma unroll
        for (int it = 0; it < 2; ++it) {
            const int u = it * 256 + tid;
            const int row = u >> 2, cc = u & 3;
            const unsigned dst = (unsigned)((it * 256 + w * 64) * 16);
            gload_lds16(A + (size_t)(bm + row) * DM + k0 + cc * 8, asA + dst);
            gload_lds16(B + (size_t)(bn + row) * DM + k0 + cc * 8, asB + dst);
        }
        __syncthreads();
        bf16x8v af[4], bf[4];
#pragma unroll
        for (int m = 0; m < 4; ++m)
            af[m] = *(const bf16x8v*)&As[(wr * 64 + m * 16 + a16) * 32 + g * 8];
#pragma unroll
        for (int n = 0; n < 4; ++n)
            bf[n] = *(const bf16x8v*)&Bs[(wc * 64 + n * 16 + a16) * 32 + g * 8];
#pragma unroll
        for (int m = 0; m < 4; ++m)
#pragma unroll
            for (int n = 0; n < 4; ++n)
                acc[m][n] = __builtin_amdgcn_mfma_f32_16x16x32_bf16(af[m], bf[n], acc[m][n], 0, 0, 0);
    }
#pragma unroll
    for (int m = 0; m < 4; ++m) {
        const int row0 = bm + wr * 64 + m * 16 + g * 4;
#pragma unroll
        for (int r = 0; r < 4; ++r) {
            const int row = row0 + r;
            const float wk = wts[(size_t)row * NPATH + path];
#pragma unroll
            for (int n = 0; n < 4; ++n) {
                const int col = bn + wc * 64 + n * 16 + a16;
                const float v = (acc[m][n][r] + bias[col]) * wk;
                const size_t oi = (size_t)row * DM + col;
                if (first) out[oi] = v; else out[oi] += v;
            }
        }
    }
}

// bf16 MFMA flash attention v8: QBLK=128, no-max softmax, T14 prefetch.
__device__ __forceinline__ void attn_body(
    const __bf16* __restrict__ qkv, __bf16* __restrict__ O, int id, char* smem)
{
    __bf16* Ks = (__bf16*)smem;                  //  9216 B (64*72)
    __bf16* Vt = (__bf16*)(smem + 9216);         //  9216 B
    __bf16* Pq = (__bf16*)(smem + 18432);        // 18432 B (4 * 32*72)
    const int tid = threadIdx.x;
    const int l = tid & 63, w = tid >> 6;
    const int a = l & 15, g = l >> 4;
    const int bh = id >> 3;
    const int b = bh >> 3, h = bh & 7;
    const int qb = (id & 7) << 7;
    const size_t base = (size_t)b * SEQ * TD;

    bf16x8v qA0, qA1, qB0, qB1;
    {
        const __bf16* qp = qkv + base + (size_t)(qb + w * 32 + a) * TD + h * 64 + g * 8;
        qA0 = *(const bf16x8v*)qp;
        qA1 = *(const bf16x8v*)(qp + 32);
        const __bf16* qp2 = qp + (size_t)16 * TD;
        qB0 = *(const bf16x8v*)qp2;
        qB1 = *(const bf16x8v*)(qp2 + 32);
    }
    float lA = 0.f, lB = 0.f;
    f32x4v oA[4] = {}, oB[4] = {};
    __bf16* pw = Pq + w * (32 * 72);
    const int sc8 = tid & 7;
    const int sr  = tid >> 3;
    const int vcol8 = (sr >> 2) ^ sc8;

    bf16x8v kpre0, kpre1, vpre0, vpre1;
    {
        const __bf16* kp0 = qkv + base + (size_t)sr * TD + DM + h * 64 + sc8 * 8;
        kpre0 = *(const bf16x8v*)kp0;
        kpre1 = *(const bf16x8v*)(kp0 + (size_t)32 * TD);
        const __bf16* vp0 = qkv + base + (size_t)(2 * sr) * TD + 2 * DM + h * 64 + sc8 * 8;
        vpre0 = *(const bf16x8v*)vp0;
        vpre1 = *(const bf16x8v*)(vp0 + TD);
    }

    for (int kt = 0; kt < SEQ; kt += 64) {
        __syncthreads();
        *(bf16x8v*)&Ks[sr * 72 + sc8 * 8] = kpre0;
        *(bf16x8v*)&Ks[(32 + sr) * 72 + sc8 * 8] = kpre1;
        {
            const u16x8 v0 = __builtin_bit_cast(u16x8, vpre0);
            const u16x8 v1 = __builtin_bit_cast(u16x8, vpre1);
#pragma unroll
            for (int j = 0; j < 8; ++j) {
                const unsigned pk = (unsigned)v0[j] | ((unsigned)v1[j] << 16);
                *(unsigned*)&Vt[(sc8 * 8 + j) * 72 + vcol8 * 8 + (sr & 3) * 2] = pk;
            }
        }
        if (kt + 64 < SEQ) {
            const __bf16* kp0 = qkv + base + (size_t)(kt + 64 + sr) * TD + DM + h * 64 + sc8 * 8;
            kpre0 = *(const bf16x8v*)kp0;
            kpre1 = *(const bf16x8v*)(kp0 + (size_t)32 * TD);
            const __bf16* vp0 = qkv + base + (size_t)(kt + 64 + 2 * sr) * TD + 2 * DM + h * 64 + sc8 * 8;
            vpre0 = *(const bf16x8v*)vp0;
            vpre1 = *(const bf16x8v*)(vp0 + TD);
        }
        __syncthreads();

        f32x4v sA[4] = {}, sB[4] = {};
        __builtin_amdgcn_s_setprio(1);
#pragma unroll
        for (int kc = 0; kc < 4; ++kc) {
            const bf16x8v kf0 = *(const bf16x8v*)&Ks[(kc * 16 + a) * 72 + g * 8];
            const bf16x8v kf1 = *(const bf16x8v*)&Ks[(kc * 16 + a) * 72 + 32 + g * 8];
            sA[kc] = __builtin_amdgcn_mfma_f32_16x16x32_bf16(kf0, qA0, sA[kc], 0, 0, 0);
            sA[kc] = __builtin_amdgcn_mfma_f32_16x16x32_bf16(kf1, qA1, sA[kc], 0, 0, 0);
            sB[kc] = __builtin_amdgcn_mfma_f32_16x16x32_bf16(kf0, qB0, sB[kc], 0, 0, 0);
            sB[kc] = __builtin_amdgcn_mfma_f32_16x16x32_bf16(kf1, qB1, sB[kc], 0, 0, 0);
        }
        __builtin_amdgcn_s_setprio(0);

        float lsumA = 0.f, lsumB = 0.f;
#pragma unroll
        for (int kc = 0; kc < 4; ++kc) {
            bf16x4v pkA, pkB;
#pragma unroll
            for (int r = 0; r < 4; ++r) {
                const float pA = __expf(sA[kc][r]);
                const float pB = __expf(sB[kc][r]);
                lsumA += pA; lsumB += pB;
                pkA[r] = (__bf16)pA; pkB[r] = (__bf16)pB;
            }
            *(bf16x4v*)&pw[a * 72 + kc * 16 + g * 4] = pkA;
            *(bf16x4v*)&pw[(16 + a) * 72 + kc * 16 + g * 4] = pkB;
        }
        lsumA += __shfl_xor(lsumA, 16);
        lsumA += __shfl_xor(lsumA, 32);
        lsumB += __shfl_xor(lsumB, 16);
        lsumB += __shfl_xor(lsumB, 32);
        lA += lsumA; lB += lsumB;
        asm volatile("s_waitcnt lgkmcnt(0)" ::: "memory");

        __builtin_amdgcn_s_setprio(1);
#pragma unroll
        for (int dc = 0; dc < 4; ++dc) {
            const int vrow = dc * 16 + a;
#pragma unroll
            for (int kh = 0; kh < 2; ++kh) {
                const bf16x8v vf = *(const bf16x8v*)&Vt[vrow * 72 + ((((kh << 2) + g) ^ ((vrow >> 3) & 7)) & 7) * 8];
                const bf16x8v paA = *(const bf16x8v*)&pw[a * 72 + kh * 32 + g * 8];
                const bf16x8v paB = *(const bf16x8v*)&pw[(16 + a) * 72 + kh * 32 + g * 8];
                oA[dc] = __builtin_amdgcn_mfma_f32_16x16x32_bf16(paA, vf, oA[dc], 0, 0, 0);
                oB[dc] = __builtin_amdgcn_mfma_f32_16x16x32_bf16(paB, vf, oB[dc], 0, 0, 0);
            }
        }
        __builtin_amdgcn_s_setprio(0);
    }

    float liA[4], liB[4];
#pragma unroll
    for (int r = 0; r < 4; ++r) {
        liA[r] = 1.f / __shfl(lA, 4 * g + r);
        liB[r] = 1.f / __shfl(lB, 4 * g + r);
    }
    const int row0 = qb + w * 32 + g * 4;
#pragma unroll
    for (int dc = 0; dc < 4; ++dc)
#pragma unroll
        for (int r = 0; r < 4; ++r) {
            O[(size_t)(b * SEQ + row0 + r) * DM + h * 64 + dc * 16 + a] = (__bf16)(oA[dc][r] * liA[r]);
            O[(size_t)(b * SEQ + row0 + 16 + r) * DM + h * 64 + dc * 16 + a] = (__bf16)(oB[dc][r] * liB[r]);
        }
}

// Standalone wrappers (small-ws fallback path)
__global__ __launch_bounds__(256)
void gemm_bf16_qkv(const __bf16* __restrict__ A, const __bf16* __restrict__ B,
                   const float* __restrict__ bias, __bf16* __restrict__ C,
                   int N, int K)
{
    __shared__ __attribute__((aligned(16))) char smem[16384];
    qkv_body(A, B, bias, C, N, K, blockIdx.x, blockIdx.y, smem);
}

__global__ __launch_bounds__(256)
void gemm_bf16_out(const __bf16* __restrict__ A, const __bf16* __restrict__ B,
                   const float* __restrict__ bias, const float* __restrict__ wts,
                   float* __restrict__ out, int path, int first)
{
    __shared__ __attribute__((aligned(16))) char smem[16384];
    out_body(A, B, bias, wts, out, path, first, blockIdx.x, blockIdx.y, smem);
}

__global__ __launch_bounds__(256)
void attn_bf16(const __bf16* __restrict__ qkv, __bf16* __restrict__ O)
{
    __shared__ __attribute__((aligned(16))) char smem[36864];
    attn_body(qkv, O, blockIdx.y * 8 + blockIdx.x, smem);
}

// ---------------------------------------------------------------------------
// Fused pathway dispatcher: one launch runs attn(pa) + qkv(pq) + out(po)
// (mutually independent pathways via double-buffered qkv/obuf).
// ---------------------------------------------------------------------------
__global__ __launch_bounds__(256)
void fused_path(const __bf16* __restrict__ xb,
                const __bf16* __restrict__ wqkv_all, const float* __restrict__ p_in_b,
                const __bf16* __restrict__ wout_all, const float* __restrict__ p_out_b,
                const float* __restrict__ wts, float* __restrict__ out,
                __bf16* __restrict__ qkv0, __bf16* __restrict__ qkv1,
                __bf16* __restrict__ ob0, __bf16* __restrict__ ob1,
                int nA, int nQ, int pq, int pa, int po)
{
    __shared__ __attribute__((aligned(16))) char smem[36864];
    const int id = blockIdx.x;
    if (id < nA) {
        const __bf16* qkvb = (pa & 1) ? qkv1 : qkv0;
        __bf16* Ob = (pa & 1) ? ob1 : ob0;
        attn_body(qkvb, Ob, id, smem);
    } else if (id < nA + nQ) {
        const int qid = id - nA;
        __bf16* C = (pq & 1) ? qkv1 : qkv0;
        qkv_body(xb, wqkv_all + (size_t)pq * TD * DM, p_in_b + (size_t)pq * TD,
                 C, TD, DM, qid % 12, qid / 12, smem);
    } else {
        const int oid = id - nA - nQ;
        const __bf16* Ab = (po & 1) ? ob1 : ob0;
        out_body(Ab, wout_all + (size_t)po * DM * DM, p_out_b + (size_t)po * DM,
                 wts, out, po, po == 0, oid & 3, oid >> 2, smem);
    }
}

// ---------------------------------------------------------------------------
extern "C" void kernel_launch(void* const* d_in, const int* in_sizes, int n_in,
                              void* d_out, int out_size, void* d_ws, size_t ws_size,
                              hipStream_t stream)
{
    const float* x         = (const float*)d_in[0];
    const float* ctx_in_w  = (const float*)d_in[1];
    const float* ctx_in_b  = (const float*)d_in[2];
    const float* ctx_out_w = (const float*)d_in[3];
    const float* ctx_out_b = (const float*)d_in[4];
    const float* r_w1      = (const float*)d_in[5];
    const float* r_b1      = (const float*)d_in[6];
    const float* r_w2      = (const float*)d_in[7];
    const float* r_b2      = (const float*)d_in[8];
    const float* r_w3      = (const float*)d_in[9];
    const float* r_b3      = (const float*)d_in[10];
    const float* p_in_w    = (const float*)d_in[11];
    const float* p_in_b    = (const float*)d_in[12];
    const float* p_out_w   = (const float*)d_in[13];
    const float* p_out_b   = (const float*)d_in[14];

    float* out  = (float*)d_out;
    float* loss = out + (size_t)TOKENS * DM;
    float* wts  = loss + 1;

    float* F = (float*)d_ws;
    float* qkvbuf   = F;                            // 12,582,912 f32 (router)
    float* obuf     = F + 12582912;                 //  4,194,304 f32 (router)
    float* attended = F;                            // overlays (router only)
    float* h1       = F + 4194304;
    float* h2       = F + 5242880;
    float* scores   = F + 5767168;
    float* freq     = F + 5898240;

    const int M = TOKENS;
    dim3 blk(256);
    const bool big = ws_size >= (size_t)134217728;  // 128 MB

    // ---- Router (fp32-exact) ----
    hipMemsetAsync(freq, 0, NPATH * sizeof(float), stream);
    gemm_f32_nt<0><<<dim3(TD / 128, M / 128), blk, 0, stream>>>(
        x, ctx_in_w, ctx_in_b, qkvbuf, M, TD, DM, DM, DM, TD, 1.f, 0, 0);
    if (big) {
        float* Sbuf = F + 16777216;                 // 64 MB
        gemm_f32_nt<1><<<dim3(8, 8, 16), blk, 0, stream>>>(
            qkvbuf, qkvbuf, nullptr, Sbuf, SEQ, SEQ, 256, TD, TD, SEQ, 0.0625f, 0, 1);
        softmax_rows<<<dim3(16 * SEQ / 4), blk, 0, stream>>>(Sbuf);
        gemm_f32_pv<<<dim3(2, 8, 16), blk, 0, stream>>>(Sbuf, qkvbuf, obuf);
    } else {
        flash_attn<256><<<dim3(SEQ / 32, 8 * 2), blk, 0, stream>>>(qkvbuf, obuf, 2, 1.f / 16.f);
    }
    gemm_f32_nt<1><<<dim3(DM / 128, M / 128), blk, 0, stream>>>(
        obuf, ctx_out_w, ctx_out_b, attended, M, DM, DM, DM, DM, DM, 1.f, 0, 0);
    gemm_f32_nt<1><<<dim3(1, M / 128), blk, 0, stream>>>(
        attended, r_w1, r_b1, h1, M, 128, DM, DM, DM, 128, 1.f, 1, 0);
    gemm_f32<<<dim3(1, M / 64), blk, 0, stream>>>(h1, r_w2, r_b2, h2, M, 64, 128, 1);
    gemm_f32<<<dim3(1, M / 64), blk, 0, stream>>>(h2, r_w3, r_b3, scores, M, NPATH, 64, 0);
    router_epilogue<<<dim3(TOKENS / 256), blk, 0, stream>>>(scores, freq, wts);
    glbl_loss_kernel<<<dim3(1), dim3(64), 0, stream>>>(freq, loss);

    // ---- Pathways (bf16 MFMA) ----
    if (big) {
        __bf16* xb       = (__bf16*)F;                  // [0, 2,097,152)
        __bf16* qkv0     = (__bf16*)(F + 2097152);      // [2.10M, 8.39M)
        __bf16* ob0      = (__bf16*)(F + 8388608);      // [8.39M, 10.49M)
        __bf16* wqkv_all = (__bf16*)(F + 16777216);     // [16.78M, 23.07M)
        __bf16* wout_all = (__bf16*)(F + 23068672);     // [23.07M, 25.17M)
        __bf16* qkv1     = (__bf16*)(F + 25165824);     // [25.17M, 31.46M)
        __bf16* ob1      = (__bf16*)(F + 31457280);     // [31.46M, 33.55M)
        cast_f32_bf16<<<dim3(TOKENS * DM / 4 / 256), blk, 0, stream>>>(x, xb, TOKENS * DM);
        cast_f32_bf16<<<dim3(NPATH * TD * DM / 4 / 256), blk, 0, stream>>>(
            p_in_w, wqkv_all, NPATH * TD * DM);
        cast_f32_bf16<<<dim3(NPATH * DM * DM / 4 / 256), blk, 0, stream>>>(
            p_out_w, wout_all, NPATH * DM * DM);
        for (int k = 0; k < NPATH + 2; ++k) {
            const int pq = (k < NPATH) ? k : -1;
            const int pa = (k >= 1 && k <= NPATH) ? k - 1 : -1;
            const int po = (k >= 2) ? k - 2 : -1;
            const int nA = (pa >= 0) ? 512 : 0;
            const int nQ = (pq >= 0) ? 768 : 0;
            const int nO = (po >= 0) ? 256 : 0;
            fused_path<<<dim3(nA + nQ + nO), blk, 0, stream>>>(
                xb, wqkv_all, p_in_b, wout_all, p_out_b, wts, out,
                qkv0, qkv1, ob0, ob1, nA, nQ, pq, pa, po);
        }
    } else {
        __bf16* xb     = (__bf16*)F;
        __bf16* qkv_b  = (__bf16*)(F + 2097152);
        __bf16* obuf_b = (__bf16*)(F + 8388608);
        __bf16* wqkv_b = (__bf16*)(F + 12582912);
        __bf16* wout_b = (__bf16*)(F + 12976128);
        cast_f32_bf16<<<dim3(TOKENS * DM / 4 / 256), blk, 0, stream>>>(x, xb, TOKENS * DM);
        for (int p = 0; p < NPATH; ++p) {
            cast_f32_bf16<<<dim3(TD * DM / 4 / 256), blk, 0, stream>>>(
                p_in_w + (size_t)p * TD * DM, wqkv_b, TD * DM);
            cast_f32_bf16<<<dim3(DM * DM / 4 / 256), blk, 0, stream>>>(
                p_out_w + (size_t)p * DM * DM, wout_b, DM * DM);
            gemm_bf16_qkv<<<dim3(TD / 128, M / 128), blk, 0, stream>>>(
                xb, wqkv_b, p_in_b + (size_t)p * TD, qkv_b, TD, DM);
            attn_bf16<<<dim3(SEQ / 128, 64), blk, 0, stream>>>(qkv_b, obuf_b);
            gemm_bf16_out<<<dim3(DM / 128, M / 128), blk, 0, stream>>>(
                obuf_b, wout_b, p_out_b + (size_t)p * DM, wts, out, p, p == 0);
        }
    }
}

// Round 19
// 1920.107 us; speedup vs baseline: 1.0861x; 1.0014x over previous
//
#include <hip/hip_runtime.h>
#include <math.h>

#define TOKENS 8192
#define DM 512
#define TD 1536
#define SEQ 1024
#define NPATH 16
#define TOPK 8

typedef __bf16 bf16x8v __attribute__((ext_vector_type(8)));
typedef __bf16 bf16x4v __attribute__((ext_vector_type(4)));
typedef float f32x4v __attribute__((ext_vector_type(4)));
typedef unsigned short u16x8 __attribute__((ext_vector_type(8)));

__device__ __forceinline__ void gload_lds16(const void* gp, unsigned lds_byte_off) {
    __builtin_amdgcn_global_load_lds(
        (const __attribute__((address_space(1))) unsigned int*)(uintptr_t)gp,
        (__attribute__((address_space(3))) unsigned int*)(uintptr_t)lds_byte_off,
        16, 0, 0);
}

// ---------------------------------------------------------------------------
// fp32 NT GEMM (R15-proven): PREF=1 register dbuf for latency-exposed
// dispatches; PREF=0 plain. zmode=1: batched router QK^T.
// ---------------------------------------------------------------------------
template <int PREF>
__global__ __launch_bounds__(256)
void gemm_f32_nt(const float* __restrict__ A, const float* __restrict__ B,
                 const float* __restrict__ bias, float* __restrict__ C,
                 int M, int N, int K, int lda, int ldb, int ldc,
                 float alpha, int relu, int zmode)
{
    __shared__ float As[16][132];
    __shared__ float Bs[16][132];
    if (zmode == 1) {
        const int z = blockIdx.z, bb = z >> 1, hh = z & 1;
        A += (size_t)bb * SEQ * TD + hh * 256;
        B += (size_t)bb * SEQ * TD + 512 + hh * 256;
        C += (size_t)z * SEQ * SEQ;
    }
    const int tid = threadIdx.x;
    const int bm = blockIdx.y << 7, bn = blockIdx.x << 7;
    const int tx4 = (tid & 15) << 2, ty4 = ((tid >> 4) & 15) << 2;
    float acc[8][8] = {};

    if constexpr (PREF) {
        const int srow = tid >> 2, skc4 = (tid & 3) << 2;
        const float* Ap = A + (size_t)(bm + srow) * lda + skc4;
        const float* Ap2 = A + (size_t)(bm + 64 + srow) * lda + skc4;
        const float* Bp = B + (size_t)(bn + srow) * ldb + skc4;
        const float* Bp2 = B + (size_t)(bn + 64 + srow) * ldb + skc4;
        float4 pa0 = *(const float4*)Ap,  pa1 = *(const float4*)Ap2;
        float4 pb0 = *(const float4*)Bp,  pb1 = *(const float4*)Bp2;
        for (int k0 = 0; k0 < K; k0 += 16) {
            __syncthreads();
            As[skc4 + 0][srow] = pa0.x; As[skc4 + 1][srow] = pa0.y;
            As[skc4 + 2][srow] = pa0.z; As[skc4 + 3][srow] = pa0.w;
            As[skc4 + 0][64 + srow] = pa1.x; As[skc4 + 1][64 + srow] = pa1.y;
            As[skc4 + 2][64 + srow] = pa1.z; As[skc4 + 3][64 + srow] = pa1.w;
            Bs[skc4 + 0][srow] = pb0.x; Bs[skc4 + 1][srow] = pb0.y;
            Bs[skc4 + 2][srow] = pb0.z; Bs[skc4 + 3][srow] = pb0.w;
            Bs[skc4 + 0][64 + srow] = pb1.x; Bs[skc4 + 1][64 + srow] = pb1.y;
            Bs[skc4 + 2][64 + srow] = pb1.z; Bs[skc4 + 3][64 + srow] = pb1.w;
            if (k0 + 16 < K) {
                pa0 = *(const float4*)(Ap + k0 + 16);
                pa1 = *(const float4*)(Ap2 + k0 + 16);
                pb0 = *(const float4*)(Bp + k0 + 16);
                pb1 = *(const float4*)(Bp2 + k0 + 16);
            }
            __syncthreads();
#pragma unroll
            for (int kk = 0; kk < 16; ++kk) {
                const float4 a0 = *(const float4*)&As[kk][ty4];
                const float4 a1 = *(const float4*)&As[kk][64 + ty4];
                const float4 b0 = *(const float4*)&Bs[kk][tx4];
                const float4 b1 = *(const float4*)&Bs[kk][64 + tx4];
                const float aa[8] = {a0.x, a0.y, a0.z, a0.w, a1.x, a1.y, a1.z, a1.w};
                const float bb[8] = {b0.x, b0.y, b0.z, b0.w, b1.x, b1.y, b1.z, b1.w};
#pragma unroll
                for (int i = 0; i < 8; ++i)
#pragma unroll
                    for (int j = 0; j < 8; ++j)
                        acc[i][j] = fmaf(aa[i], bb[j], acc[i][j]);
            }
        }
    } else {
        for (int k0 = 0; k0 < K; k0 += 16) {
            __syncthreads();
#pragma unroll
            for (int it = 0; it < 2; ++it) {
                const int u = (it << 8) + tid;
                const int row = u >> 2, kc4 = (u & 3) << 2;
                const float4 av = *(const float4*)(A + (size_t)(bm + row) * lda + k0 + kc4);
                As[kc4 + 0][row] = av.x; As[kc4 + 1][row] = av.y;
                As[kc4 + 2][row] = av.z; As[kc4 + 3][row] = av.w;
                const float4 bv = *(const float4*)(B + (size_t)(bn + row) * ldb + k0 + kc4);
                Bs[kc4 + 0][row] = bv.x; Bs[kc4 + 1][row] = bv.y;
                Bs[kc4 + 2][row] = bv.z; Bs[kc4 + 3][row] = bv.w;
            }
            __syncthreads();
#pragma unroll
            for (int kk = 0; kk < 16; ++kk) {
                const float4 a0 = *(const float4*)&As[kk][ty4];
                const float4 a1 = *(const float4*)&As[kk][64 + ty4];
                const float4 b0 = *(const float4*)&Bs[kk][tx4];
                const float4 b1 = *(const float4*)&Bs[kk][64 + tx4];
                const float aa[8] = {a0.x, a0.y, a0.z, a0.w, a1.x, a1.y, a1.z, a1.w};
                const float bb[8] = {b0.x, b0.y, b0.z, b0.w, b1.x, b1.y, b1.z, b1.w};
#pragma unroll
                for (int i = 0; i < 8; ++i)
#pragma unroll
                    for (int j = 0; j < 8; ++j)
                        acc[i][j] = fmaf(aa[i], bb[j], acc[i][j]);
            }
        }
    }

    float bcol[8] = {};
    if (bias) {
        const float4 bL = *(const float4*)(bias + bn + tx4);
        const float4 bH = *(const float4*)(bias + bn + 64 + tx4);
        bcol[0] = bL.x; bcol[1] = bL.y; bcol[2] = bL.z; bcol[3] = bL.w;
        bcol[4] = bH.x; bcol[5] = bH.y; bcol[6] = bH.z; bcol[7] = bH.w;
    }
#pragma unroll
    for (int i = 0; i < 8; ++i) {
        const int row = bm + ((i < 4) ? (ty4 + i) : (64 + ty4 + i - 4));
        float* cp = C + (size_t)row * ldc + bn;
        float v[8];
#pragma unroll
        for (int j = 0; j < 8; ++j) {
            v[j] = alpha * acc[i][j] + bcol[j];
            if (relu) v[j] = fmaxf(v[j], 0.f);
        }
        *(float4*)(cp + tx4) = make_float4(v[0], v[1], v[2], v[3]);
        *(float4*)(cp + 64 + tx4) = make_float4(v[4], v[5], v[6], v[7]);
    }
}

// ---------------------------------------------------------------------------
// fp32 NN GEMM (router PV), batched z; register prefetch.
// ---------------------------------------------------------------------------
__global__ __launch_bounds__(256)
void gemm_f32_pv(const float* __restrict__ Sb, const float* __restrict__ qkv,
                 float* __restrict__ obuf)
{
    __shared__ float As[16][132];
    __shared__ float Bs[16][128];
    const int z = blockIdx.z, bb = z >> 1, hh = z & 1;
    const float* A = Sb + (size_t)z * SEQ * SEQ;
    const float* B = qkv + (size_t)bb * SEQ * TD + 1024 + hh * 256;
    float* C = obuf + (size_t)bb * SEQ * 512 + hh * 256;
    const int tid = threadIdx.x;
    const int bm = blockIdx.y << 7, bn = blockIdx.x << 7;
    const int tx4 = (tid & 15) << 2, ty4 = ((tid >> 4) & 15) << 2;
    const int ar = tid >> 2, ak4 = (tid & 3) << 2;
    const int br = tid >> 5, bn4 = (tid & 31) << 2;
    const float* ApA  = A + (size_t)(bm + ar) * SEQ + ak4;
    const float* ApA2 = A + (size_t)(bm + 64 + ar) * SEQ + ak4;
    const float* BpB  = B + (size_t)br * TD + bn + bn4;
    const float* BpB2 = B + (size_t)(8 + br) * TD + bn + bn4;

    float4 a0 = *(const float4*)ApA, a1 = *(const float4*)ApA2;
    float4 b0 = *(const float4*)BpB, b1 = *(const float4*)BpB2;

    float acc[8][8] = {};
    for (int k0 = 0; k0 < SEQ; k0 += 16) {
        __syncthreads();
        As[ak4 + 0][ar] = a0.x; As[ak4 + 1][ar] = a0.y;
        As[ak4 + 2][ar] = a0.z; As[ak4 + 3][ar] = a0.w;
        As[ak4 + 0][64 + ar] = a1.x; As[ak4 + 1][64 + ar] = a1.y;
        As[ak4 + 2][64 + ar] = a1.z; As[ak4 + 3][64 + ar] = a1.w;
        *(float4*)&Bs[br][bn4] = b0;
        *(float4*)&Bs[8 + br][bn4] = b1;
        if (k0 + 16 < SEQ) {
            a0 = *(const float4*)(ApA + k0 + 16);
            a1 = *(const float4*)(ApA2 + k0 + 16);
            b0 = *(const float4*)(BpB + (size_t)(k0 + 16) * TD);
            b1 = *(const float4*)(BpB2 + (size_t)(k0 + 16) * TD);
        }
        __syncthreads();
#pragma unroll
        for (int kk = 0; kk < 16; ++kk) {
            const float4 A0 = *(const float4*)&As[kk][ty4];
            const float4 A1 = *(const float4*)&As[kk][64 + ty4];
            const float4 B0 = *(const float4*)&Bs[kk][tx4];
            const float4 B1 = *(const float4*)&Bs[kk][64 + tx4];
            const float aa[8] = {A0.x, A0.y, A0.z, A0.w, A1.x, A1.y, A1.z, A1.w};
            const float bb[8] = {B0.x, B0.y, B0.z, B0.w, B1.x, B1.y, B1.z, B1.w};
#pragma unroll
            for (int i = 0; i < 8; ++i)
#pragma unroll
                for (int j = 0; j < 8; ++j)
                    acc[i][j] = fmaf(aa[i], bb[j], acc[i][j]);
        }
    }
#pragma unroll
    for (int i = 0; i < 8; ++i) {
        const int row = bm + ((i < 4) ? (ty4 + i) : (64 + ty4 + i - 4));
        float* cp = C + (size_t)row * 512 + bn;
        *(float4*)(cp + tx4) = make_float4(acc[i][0], acc[i][1], acc[i][2], acc[i][3]);
        *(float4*)(cp + 64 + tx4) = make_float4(acc[i][4], acc[i][5], acc[i][6], acc[i][7]);
    }
}

// Row softmax over 1024 cols, in-place. One wave per row.
__global__ __launch_bounds__(256)
void softmax_rows(float* __restrict__ S_)
{
    const int row = blockIdx.x * 4 + (threadIdx.x >> 6);
    const int lane = threadIdx.x & 63;
    float* rp = S_ + (size_t)row * 1024 + lane * 16;
    float4 v[4];
#pragma unroll
    for (int i = 0; i < 4; ++i) v[i] = *(const float4*)(rp + i * 4);
    float mx = -INFINITY;
#pragma unroll
    for (int i = 0; i < 4; ++i)
        mx = fmaxf(mx, fmaxf(fmaxf(v[i].x, v[i].y), fmaxf(v[i].z, v[i].w)));
#pragma unroll
    for (int off = 1; off < 64; off <<= 1) mx = fmaxf(mx, __shfl_xor(mx, off));
    float sum = 0.f;
#pragma unroll
    for (int i = 0; i < 4; ++i) {
        v[i].x = __expf(v[i].x - mx); v[i].y = __expf(v[i].y - mx);
        v[i].z = __expf(v[i].z - mx); v[i].w = __expf(v[i].w - mx);
        sum += v[i].x + v[i].y + v[i].z + v[i].w;
    }
#pragma unroll
    for (int off = 1; off < 64; off <<= 1) sum += __shfl_xor(sum, off);
    const float inv = 1.f / sum;
#pragma unroll
    for (int i = 0; i < 4; ++i) {
        v[i].x *= inv; v[i].y *= inv; v[i].z *= inv; v[i].w *= inv;
        *(float4*)(rp + i * 4) = v[i];
    }
}

// ---------------------------------------------------------------------------
// fp32 GEMM 64x64 (small router layers r_w2/r_w3).
// ---------------------------------------------------------------------------
__global__ __launch_bounds__(256)
void gemm_f32(const float* __restrict__ A, const float* __restrict__ W,
              const float* __restrict__ bias, float* __restrict__ C,
              int M, int N, int K, int relu)
{
    __shared__ float As[16][64];
    __shared__ float Bs[16][64];
    const int bm = blockIdx.y << 6;
    const int bn = blockIdx.x << 6;
    const int tid = threadIdx.x;
    const int tx = tid & 15, ty = tid >> 4;
    const int lr = tid >> 2;
    const int lc = (tid & 3) << 2;
    float acc[4][4] = {};
    for (int k0 = 0; k0 < K; k0 += 16) {
        float4 av = *(const float4*)(A + (size_t)(bm + lr) * K + (k0 + lc));
        float4 bv = make_float4(0.f, 0.f, 0.f, 0.f);
        const int wr = bn + lr;
        if (wr < N) bv = *(const float4*)(W + (size_t)wr * K + (k0 + lc));
        __syncthreads();
        As[lc + 0][lr] = av.x; As[lc + 1][lr] = av.y;
        As[lc + 2][lr] = av.z; As[lc + 3][lr] = av.w;
        Bs[lc + 0][lr] = bv.x; Bs[lc + 1][lr] = bv.y;
        Bs[lc + 2][lr] = bv.z; Bs[lc + 3][lr] = bv.w;
        __syncthreads();
#pragma unroll
        for (int kk = 0; kk < 16; ++kk) {
            const float4 a4 = *(const float4*)(&As[kk][ty << 2]);
            const float4 b4 = *(const float4*)(&Bs[kk][tx << 2]);
            const float a[4] = {a4.x, a4.y, a4.z, a4.w};
            const float b[4] = {b4.x, b4.y, b4.z, b4.w};
#pragma unroll
            for (int i = 0; i < 4; ++i)
#pragma unroll
                for (int j = 0; j < 4; ++j)
                    acc[i][j] = fmaf(a[i], b[j], acc[i][j]);
        }
    }
#pragma unroll
    for (int i = 0; i < 4; ++i) {
        const int m = bm + (ty << 2) + i;
#pragma unroll
        for (int j = 0; j < 4; ++j) {
            const int n = bn + (tx << 2) + j;
            if (n < N) {
                float v = acc[i][j] + bias[n];
                if (relu) v = fmaxf(v, 0.f);
                C[(size_t)m * N + n] = v;
            }
        }
    }
}

// ---------------------------------------------------------------------------
// fp32 flash attention fallback (router ctx, DH=256) — used when ws is small.
// ---------------------------------------------------------------------------
template <int DH>
__global__ __launch_bounds__(256)
void flash_attn(const float* __restrict__ qkv, float* __restrict__ O,
                int H, float scale)
{
    constexpr int NU = DH / 64;
    __shared__ float Qs[32][DH + 4];
    __shared__ float Ks[32][DH + 4];
    __shared__ float Vs[32][DH + 4];
    __shared__ float Ps[32][33];
    const int tid = threadIdx.x;
    const int g2 = tid & 15;
    const int rs = tid >> 4;
    const int bh = blockIdx.y;
    const int b = bh / H, h = bh - b * H;
    const int rb = blockIdx.x << 5;
    const float* qb = qkv + (size_t)b * SEQ * TD + (size_t)h * DH;
    const float* kb = qb + DM;
    const float* vb = qb + 2 * DM;

    for (int idx = tid; idx < 32 * (DH / 4); idx += 256) {
        const int rr = idx / (DH / 4);
        const int dp = (idx - rr * (DH / 4)) << 2;
        float4 v = *(const float4*)(qb + (size_t)(rb + rr) * TD + dp);
        v.x *= scale; v.y *= scale; v.z *= scale; v.w *= scale;
        *(float4*)&Qs[rr][dp] = v;
    }
    float m0 = -INFINITY, m1 = -INFINITY, l0 = 0.f, l1 = 0.f;
    float4 o0[NU], o1[NU];
#pragma unroll
    for (int u = 0; u < NU; ++u) {
        o0[u] = make_float4(0.f, 0.f, 0.f, 0.f);
        o1[u] = make_float4(0.f, 0.f, 0.f, 0.f);
    }
    __syncthreads();

    for (int kt = 0; kt < SEQ; kt += 32) {
        for (int idx = tid; idx < 32 * (DH / 4); idx += 256) {
            const int rr = idx / (DH / 4);
            const int dp = (idx - rr * (DH / 4)) << 2;
            *(float4*)&Ks[rr][dp] = *(const float4*)(kb + (size_t)(kt + rr) * TD + dp);
            *(float4*)&Vs[rr][dp] = *(const float4*)(vb + (size_t)(kt + rr) * TD + dp);
        }
        __syncthreads();
        float s00 = 0.f, s01 = 0.f, s10 = 0.f, s11 = 0.f;
        const int cA = g2, cB = g2 + 16;
#pragma unroll 8
        for (int i = 0; i < DH; i += 4) {
            const float4 q0 = *(const float4*)&Qs[rs][i];
            const float4 q1 = *(const float4*)&Qs[rs + 16][i];
            const float4 k0 = *(const float4*)&Ks[cA][i];
            const float4 k1 = *(const float4*)&Ks[cB][i];
            s00 += q0.x * k0.x + q0.y * k0.y + q0.z * k0.z + q0.w * k0.w;
            s01 += q0.x * k1.x + q0.y * k1.y + q0.z * k1.z + q0.w * k1.w;
            s10 += q1.x * k0.x + q1.y * k0.y + q1.z * k0.z + q1.w * k0.w;
            s11 += q1.x * k1.x + q1.y * k1.y + q1.z * k1.z + q1.w * k1.w;
        }
        float ml0 = fmaxf(s00, s01), ml1 = fmaxf(s10, s11);
#pragma unroll
        for (int off = 1; off < 16; off <<= 1) {
            ml0 = fmaxf(ml0, __shfl_xor(ml0, off));
            ml1 = fmaxf(ml1, __shfl_xor(ml1, off));
        }
        const float n0 = fmaxf(m0, ml0), n1 = fmaxf(m1, ml1);
        const float f0 = __expf(m0 - n0), f1 = __expf(m1 - n1);
        const float p00 = __expf(s00 - n0), p01 = __expf(s01 - n0);
        const float p10 = __expf(s10 - n1), p11 = __expf(s11 - n1);
        float sum0 = p00 + p01, sum1 = p10 + p11;
#pragma unroll
        for (int off = 1; off < 16; off <<= 1) {
            sum0 += __shfl_xor(sum0, off);
            sum1 += __shfl_xor(sum1, off);
        }
        l0 = l0 * f0 + sum0; l1 = l1 * f1 + sum1;
        m0 = n0; m1 = n1;
#pragma unroll
        for (int u = 0; u < NU; ++u) {
            o0[u].x *= f0; o0[u].y *= f0; o0[u].z *= f0; o0[u].w *= f0;
            o1[u].x *= f1; o1[u].y *= f1; o1[u].z *= f1; o1[u].w *= f1;
        }
        Ps[rs][cA] = p00; Ps[rs][cB] = p01;
        Ps[rs + 16][cA] = p10; Ps[rs + 16][cB] = p11;
        __syncthreads();
#pragma unroll 4
        for (int c = 0; c < 32; ++c) {
            const float pv0 = Ps[rs][c];
            const float pv1 = Ps[rs + 16][c];
#pragma unroll
            for (int u = 0; u < NU; ++u) {
                const float4 v4 = *(const float4*)&Vs[c][(g2 << 2) + (u << 6)];
                o0[u].x = fmaf(pv0, v4.x, o0[u].x);
                o0[u].y = fmaf(pv0, v4.y, o0[u].y);
                o0[u].z = fmaf(pv0, v4.z, o0[u].z);
                o0[u].w = fmaf(pv0, v4.w, o0[u].w);
                o1[u].x = fmaf(pv1, v4.x, o1[u].x);
                o1[u].y = fmaf(pv1, v4.y, o1[u].y);
                o1[u].z = fmaf(pv1, v4.z, o1[u].z);
                o1[u].w = fmaf(pv1, v4.w, o1[u].w);
            }
        }
        __syncthreads();
    }
    const float i0 = 1.f / l0, i1 = 1.f / l1;
    float* ob0 = O + (size_t)b * SEQ * DM + (size_t)(rb + rs) * DM + h * DH;
    float* ob1 = ob0 + (size_t)16 * DM;
#pragma unroll
    for (int u = 0; u < NU; ++u) {
        float4 w0 = o0[u];
        w0.x *= i0; w0.y *= i0; w0.z *= i0; w0.w *= i0;
        *(float4*)(ob0 + (g2 << 2) + (u << 6)) = w0;
        float4 w1 = o1[u];
        w1.x *= i1; w1.y *= i1; w1.z *= i1; w1.w *= i1;
        *(float4*)(ob1 + (g2 << 2) + (u << 6)) = w1;
    }
}

// ---------------------------------------------------------------------------
// Router epilogue + loss (fp32-exact)
// ---------------------------------------------------------------------------
__global__ __launch_bounds__(256)
void router_epilogue(const float* __restrict__ scores, float* __restrict__ freq,
                     float* __restrict__ weights)
{
    const int t = blockIdx.x * 256 + threadIdx.x;
    float s[NPATH];
#pragma unroll
    for (int i = 0; i < NPATH; ++i) s[i] = scores[(size_t)t * NPATH + i];
    float mx = s[0];
#pragma unroll
    for (int i = 1; i < NPATH; ++i) mx = fmaxf(mx, s[i]);
    float p[NPATH];
    float sum = 0.f;
#pragma unroll
    for (int i = 0; i < NPATH; ++i) { p[i] = expf(s[i] - mx); sum += p[i]; }
    const float inv = 1.f / sum;
#pragma unroll
    for (int i = 0; i < NPATH; ++i) p[i] *= inv;
#pragma unroll
    for (int i = 0; i < NPATH; ++i) {
        float v = p[i];
        for (int off = 32; off >= 1; off >>= 1) v += __shfl_xor(v, off);
        if ((threadIdx.x & 63) == 0) atomicAdd(&freq[i], v);
    }
    unsigned used = 0u;
    float topv[TOPK];
    int topi[TOPK];
    float wsum = 0.f;
#pragma unroll
    for (int k = 0; k < TOPK; ++k) {
        float best = -1.f; int bi = 0;
#pragma unroll
        for (int i = 0; i < NPATH; ++i) {
            if (!((used >> i) & 1u) && p[i] > best) { best = p[i]; bi = i; }
        }
        used |= 1u << bi;
        topv[k] = best; topi[k] = bi;
        wsum += best;
    }
    const float winv = 1.f / (wsum + 1e-8f);
    float w[NPATH];
#pragma unroll
    for (int i = 0; i < NPATH; ++i) w[i] = 0.f;
#pragma unroll
    for (int k = 0; k < TOPK; ++k) w[topi[k]] = topv[k] * winv;
#pragma unroll
    for (int i = 0; i < NPATH; ++i) weights[(size_t)t * NPATH + i] = w[i];
}

__global__ void glbl_loss_kernel(const float* __restrict__ freq, float* __restrict__ out)
{
    if (threadIdx.x == 0 && blockIdx.x == 0) {
        float acc = 0.f;
        for (int i = 0; i < NPATH; ++i) {
            const float f = freq[i] * (1.f / (float)TOKENS);
            acc += f * f;
        }
        out[0] = (float)NPATH * acc;
    }
}

__global__ __launch_bounds__(256)
void cast_f32_bf16(const float* __restrict__ src, __bf16* __restrict__ dst, int n)
{
    const int i = (blockIdx.x * 256 + threadIdx.x) * 4;
    if (i < n) {
        const float4 v = *(const float4*)(src + i);
        bf16x4v o;
        o[0] = (__bf16)v.x; o[1] = (__bf16)v.y; o[2] = (__bf16)v.z; o[3] = (__bf16)v.w;
        *(bf16x4v*)(dst + i) = o;
    }
}

// ===========================================================================
// Pathway role bodies (shared by standalone kernels and the fused dispatcher)
// ===========================================================================

// bf16 MFMA GEMM: C = A@B^T + bias; cols<512 (Q) scaled x0.125.
__device__ __forceinline__ void qkv_body(
    const __bf16* __restrict__ A, const __bf16* __restrict__ B,
    const float* __restrict__ bias, __bf16* __restrict__ C,
    int N, int K, int bx, int by, char* smem)
{
    __bf16* As = (__bf16*)smem;
    __bf16* Bs = (__bf16*)(smem + 8192);
    const int tid = threadIdx.x;
    const int l = tid & 63, w = tid >> 6;
    const int wr = w >> 1, wc = w & 1;
    const int a16 = l & 15, g = l >> 4;
    const int bm = by << 7, bn = bx << 7;
    const unsigned asA = (unsigned)(uintptr_t)(void*)As;
    const unsigned asB = (unsigned)(uintptr_t)(void*)Bs;

    f32x4v acc[4][4] = {};
    for (int k0 = 0; k0 < K; k0 += 32) {
        __syncthreads();
#pragma unroll
        for (int it = 0; it < 2; ++it) {
            const int u = it * 256 + tid;
            const int row = u >> 2, cc = u & 3;
            const unsigned dst = (unsigned)((it * 256 + w * 64) * 16);
            gload_lds16(A + (size_t)(bm + row) * K + k0 + cc * 8, asA + dst);
            gload_lds16(B + (size_t)(bn + row) * K + k0 + cc * 8, asB + dst);
        }
        __syncthreads();
        bf16x8v af[4], bf[4];
#pragma unroll
        for (int m = 0; m < 4; ++m)
            af[m] = *(const bf16x8v*)&As[(wr * 64 + m * 16 + a16) * 32 + g * 8];
#pragma unroll
        for (int n = 0; n < 4; ++n)
            bf[n] = *(const bf16x8v*)&Bs[(wc * 64 + n * 16 + a16) * 32 + g * 8];
#pragma unroll
        for (int m = 0; m < 4; ++m)
#pragma unroll
            for (int n = 0; n < 4; ++n)
                acc[m][n] = __builtin_amdgcn_mfma_f32_16x16x32_bf16(af[m], bf[n], acc[m][n], 0, 0, 0);
    }
#pragma unroll
    for (int n = 0; n < 4; ++n) {
        const int col = bn + wc * 64 + n * 16 + a16;
        const float bv = bias[col];
        const float sc = (col < DM) ? 0.125f : 1.0f;   // fold 1/sqrt(64) into Q
#pragma unroll
        for (int m = 0; m < 4; ++m) {
            const int row0 = bm + wr * 64 + m * 16 + g * 4;
#pragma unroll
            for (int r = 0; r < 4; ++r)
                C[(size_t)(row0 + r) * N + col] = (__bf16)((acc[m][n][r] + bv) * sc);
        }
    }
}

// Out-projection + weighted accumulate into fp32 out.
__device__ __forceinline__ void out_body(
    const __bf16* __restrict__ A, const __bf16* __restrict__ B,
    const float* __restrict__ bias, const float* __restrict__ wts,
    float* __restrict__ out, int path, int first, int bx, int by, char* smem)
{
    __bf16* As = (__bf16*)smem;
    __bf16* Bs = (__bf16*)(smem + 8192);
    const int tid = threadIdx.x;
    const int l = tid & 63, w = tid >> 6;
    const int wr = w >> 1, wc = w & 1;
    const int a16 = l & 15, g = l >> 4;
    const int bm = by << 7, bn = bx << 7;
    const unsigned asA = (unsigned)(uintptr_t)(void*)As;
    const unsigned asB = (unsigned)(uintptr_t)(void*)Bs;

    f32x4v acc[4][4] = {};
    for (int k0 = 0; k0 < DM; k0 += 32) {
        __syncthreads();
#pragma unroll
        for (int it = 0; it < 2; ++it) {
            const int u = it * 256 + tid;
            const int row = u >> 2, cc = u & 3;
            const unsigned dst = (unsigned)((it * 256 + w * 64) * 16);
            gload_lds16(A + (size_t)(bm + row) * DM + k0 + cc * 8, asA + dst);
            gload_lds16(B + (size_t)(bn + row) * DM + k0 + cc * 8, asB + dst);
        }
        __syncthreads();
        bf16x8v af[4], bf[4];
#pragma unroll
        for (int m = 0; m < 4; ++m)
            af[m] = *(const bf16x8v*)&As[(wr * 64 + m * 16 + a16) * 32 + g * 8];
#pragma unroll
        for (int n = 0; n < 4; ++n)
            bf[n] = *(const bf16x8v*)&Bs[(wc * 64 + n * 16 + a16) * 32 + g * 8];
#pragma unroll
        for (int m = 0; m < 4; ++m)
#pragma unroll
            for (int n = 0; n < 4; ++n)
                acc[m][n] = __builtin_amdgcn_mfma_f32_16x16x32_bf16(af[m], bf[n], acc[m][n], 0, 0, 0);
    }
#pragma unroll
    for (int m = 0; m < 4; ++m) {
        const int row0 = bm + wr * 64 + m * 16 + g * 4;
#pragma unroll
        for (int r = 0; r < 4; ++r) {
            const int row = row0 + r;
            const float wk = wts[(size_t)row * NPATH + path];
#pragma unroll
            for (int n = 0; n < 4; ++n) {
                const int col = bn + wc * 64 + n * 16 + a16;
                const float v = (acc[m][n][r] + bias[col]) * wk;
                const size_t oi = (size_t)row * DM + col;
                if (first) out[oi] = v; else out[oi] += v;
            }
        }
    }
}

// bf16 MFMA flash attention v8: QBLK=128, no-max softmax, T14 prefetch.
__device__ __forceinline__ void attn_body(
    const __bf16* __restrict__ qkv, __bf16* __restrict__ O, int id, char* smem)
{
    __bf16* Ks = (__bf16*)smem;                  //  9216 B (64*72)
    __bf16* Vt = (__bf16*)(smem + 9216);         //  9216 B
    __bf16* Pq = (__bf16*)(smem + 18432);        // 18432 B (4 * 32*72)
    const int tid = threadIdx.x;
    const int l = tid & 63, w = tid >> 6;
    const int a = l & 15, g = l >> 4;
    const int bh = id >> 3;
    const int b = bh >> 3, h = bh & 7;
    const int qb = (id & 7) << 7;
    const size_t base = (size_t)b * SEQ * TD;

    bf16x8v qA0, qA1, qB0, qB1;
    {
        const __bf16* qp = qkv + base + (size_t)(qb + w * 32 + a) * TD + h * 64 + g * 8;
        qA0 = *(const bf16x8v*)qp;
        qA1 = *(const bf16x8v*)(qp + 32);
        const __bf16* qp2 = qp + (size_t)16 * TD;
        qB0 = *(const bf16x8v*)qp2;
        qB1 = *(const bf16x8v*)(qp2 + 32);
    }
    float lA = 0.f, lB = 0.f;
    f32x4v oA[4] = {}, oB[4] = {};
    __bf16* pw = Pq + w * (32 * 72);
    const int sc8 = tid & 7;
    const int sr  = tid >> 3;
    const int vcol8 = (sr >> 2) ^ sc8;

    bf16x8v kpre0, kpre1, vpre0, vpre1;
    {
        const __bf16* kp0 = qkv + base + (size_t)sr * TD + DM + h * 64 + sc8 * 8;
        kpre0 = *(const bf16x8v*)kp0;
        kpre1 = *(const bf16x8v*)(kp0 + (size_t)32 * TD);
        const __bf16* vp0 = qkv + base + (size_t)(2 * sr) * TD + 2 * DM + h * 64 + sc8 * 8;
        vpre0 = *(const bf16x8v*)vp0;
        vpre1 = *(const bf16x8v*)(vp0 + TD);
    }

    for (int kt = 0; kt < SEQ; kt += 64) {
        __syncthreads();
        *(bf16x8v*)&Ks[sr * 72 + sc8 * 8] = kpre0;
        *(bf16x8v*)&Ks[(32 + sr) * 72 + sc8 * 8] = kpre1;
        {
            const u16x8 v0 = __builtin_bit_cast(u16x8, vpre0);
            const u16x8 v1 = __builtin_bit_cast(u16x8, vpre1);
#pragma unroll
            for (int j = 0; j < 8; ++j) {
                const unsigned pk = (unsigned)v0[j] | ((unsigned)v1[j] << 16);
                *(unsigned*)&Vt[(sc8 * 8 + j) * 72 + vcol8 * 8 + (sr & 3) * 2] = pk;
            }
        }
        if (kt + 64 < SEQ) {
            const __bf16* kp0 = qkv + base + (size_t)(kt + 64 + sr) * TD + DM + h * 64 + sc8 * 8;
            kpre0 = *(const bf16x8v*)kp0;
            kpre1 = *(const bf16x8v*)(kp0 + (size_t)32 * TD);
            const __bf16* vp0 = qkv + base + (size_t)(kt + 64 + 2 * sr) * TD + 2 * DM + h * 64 + sc8 * 8;
            vpre0 = *(const bf16x8v*)vp0;
            vpre1 = *(const bf16x8v*)(vp0 + TD);
        }
        __syncthreads();

        f32x4v sA[4] = {}, sB[4] = {};
        __builtin_amdgcn_s_setprio(1);
#pragma unroll
        for (int kc = 0; kc < 4; ++kc) {
            const bf16x8v kf0 = *(const bf16x8v*)&Ks[(kc * 16 + a) * 72 + g * 8];
            const bf16x8v kf1 = *(const bf16x8v*)&Ks[(kc * 16 + a) * 72 + 32 + g * 8];
            sA[kc] = __builtin_amdgcn_mfma_f32_16x16x32_bf16(kf0, qA0, sA[kc], 0, 0, 0);
            sA[kc] = __builtin_amdgcn_mfma_f32_16x16x32_bf16(kf1, qA1, sA[kc], 0, 0, 0);
            sB[kc] = __builtin_amdgcn_mfma_f32_16x16x32_bf16(kf0, qB0, sB[kc], 0, 0, 0);
            sB[kc] = __builtin_amdgcn_mfma_f32_16x16x32_bf16(kf1, qB1, sB[kc], 0, 0, 0);
        }
        __builtin_amdgcn_s_setprio(0);

        float lsumA = 0.f, lsumB = 0.f;
#pragma unroll
        for (int kc = 0; kc < 4; ++kc) {
            bf16x4v pkA, pkB;
#pragma unroll
            for (int r = 0; r < 4; ++r) {
                const float pA = __expf(sA[kc][r]);
                const float pB = __expf(sB[kc][r]);
                lsumA += pA; lsumB += pB;
                pkA[r] = (__bf16)pA; pkB[r] = (__bf16)pB;
            }
            *(bf16x4v*)&pw[a * 72 + kc * 16 + g * 4] = pkA;
            *(bf16x4v*)&pw[(16 + a) * 72 + kc * 16 + g * 4] = pkB;
        }
        lsumA += __shfl_xor(lsumA, 16);
        lsumA += __shfl_xor(lsumA, 32);
        lsumB += __shfl_xor(lsumB, 16);
        lsumB += __shfl_xor(lsumB, 32);
        lA += lsumA; lB += lsumB;
        asm volatile("s_waitcnt lgkmcnt(0)" ::: "memory");

        __builtin_amdgcn_s_setprio(1);
#pragma unroll
        for (int dc = 0; dc < 4; ++dc) {
            const int vrow = dc * 16 + a;
#pragma unroll
            for (int kh = 0; kh < 2; ++kh) {
                const bf16x8v vf = *(const bf16x8v*)&Vt[vrow * 72 + ((((kh << 2) + g) ^ ((vrow >> 3) & 7)) & 7) * 8];
                const bf16x8v paA = *(const bf16x8v*)&pw[a * 72 + kh * 32 + g * 8];
                const bf16x8v paB = *(const bf16x8v*)&pw[(16 + a) * 72 + kh * 32 + g * 8];
                oA[dc] = __builtin_amdgcn_mfma_f32_16x16x32_bf16(paA, vf, oA[dc], 0, 0, 0);
                oB[dc] = __builtin_amdgcn_mfma_f32_16x16x32_bf16(paB, vf, oB[dc], 0, 0, 0);
            }
        }
        __builtin_amdgcn_s_setprio(0);
    }

    float liA[4], liB[4];
#pragma unroll
    for (int r = 0; r < 4; ++r) {
        liA[r] = 1.f / __shfl(lA, 4 * g + r);
        liB[r] = 1.f / __shfl(lB, 4 * g + r);
    }
    const int row0 = qb + w * 32 + g * 4;
#pragma unroll
    for (int dc = 0; dc < 4; ++dc)
#pragma unroll
        for (int r = 0; r < 4; ++r) {
            O[(size_t)(b * SEQ + row0 + r) * DM + h * 64 + dc * 16 + a] = (__bf16)(oA[dc][r] * liA[r]);
            O[(size_t)(b * SEQ + row0 + 16 + r) * DM + h * 64 + dc * 16 + a] = (__bf16)(oB[dc][r] * liB[r]);
        }
}

// Standalone wrappers (small-ws fallback path)
__global__ __launch_bounds__(256)
void gemm_bf16_qkv(const __bf16* __restrict__ A, const __bf16* __restrict__ B,
                   const float* __restrict__ bias, __bf16* __restrict__ C,
                   int N, int K)
{
    __shared__ __attribute__((aligned(16))) char smem[16384];
    qkv_body(A, B, bias, C, N, K, blockIdx.x, blockIdx.y, smem);
}

__global__ __launch_bounds__(256)
void gemm_bf16_out(const __bf16* __restrict__ A, const __bf16* __restrict__ B,
                   const float* __restrict__ bias, const float* __restrict__ wts,
                   float* __restrict__ out, int path, int first)
{
    __shared__ __attribute__((aligned(16))) char smem[16384];
    out_body(A, B, bias, wts, out, path, first, blockIdx.x, blockIdx.y, smem);
}

__global__ __launch_bounds__(256)
void attn_bf16(const __bf16* __restrict__ qkv, __bf16* __restrict__ O)
{
    __shared__ __attribute__((aligned(16))) char smem[36864];
    attn_body(qkv, O, blockIdx.y * 8 + blockIdx.x, smem);
}

// ---------------------------------------------------------------------------
// Fused pathway dispatcher: one launch runs attn(pa) + qkv(pq) + out(po)
// (mutually independent pathways via double-buffered qkv/obuf).
// ---------------------------------------------------------------------------
__global__ __launch_bounds__(256)
void fused_path(const __bf16* __restrict__ xb,
                const __bf16* __restrict__ wqkv_all, const float* __restrict__ p_in_b,
                const __bf16* __restrict__ wout_all, const float* __restrict__ p_out_b,
                const float* __restrict__ wts, float* __restrict__ out,
                __bf16* __restrict__ qkv0, __bf16* __restrict__ qkv1,
                __bf16* __restrict__ ob0, __bf16* __restrict__ ob1,
                int nA, int nQ, int pq, int pa, int po)
{
    __shared__ __attribute__((aligned(16))) char smem[36864];
    const int id = blockIdx.x;
    if (id < nA) {
        const __bf16* qkvb = (pa & 1) ? qkv1 : qkv0;
        __bf16* Ob = (pa & 1) ? ob1 : ob0;
        attn_body(qkvb, Ob, id, smem);
    } else if (id < nA + nQ) {
        const int qid = id - nA;
        __bf16* C = (pq & 1) ? qkv1 : qkv0;
        qkv_body(xb, wqkv_all + (size_t)pq * TD * DM, p_in_b + (size_t)pq * TD,
                 C, TD, DM, qid % 12, qid / 12, smem);
    } else {
        const int oid = id - nA - nQ;
        const __bf16* Ab = (po & 1) ? ob1 : ob0;
        out_body(Ab, wout_all + (size_t)po * DM * DM, p_out_b + (size_t)po * DM,
                 wts, out, po, po == 0, oid & 3, oid >> 2, smem);
    }
}

// ---------------------------------------------------------------------------
extern "C" void kernel_launch(void* const* d_in, const int* in_sizes, int n_in,
                              void* d_out, int out_size, void* d_ws, size_t ws_size,
                              hipStream_t stream)
{
    const float* x         = (const float*)d_in[0];
    const float* ctx_in_w  = (const float*)d_in[1];
    const float* ctx_in_b  = (const float*)d_in[2];
    const float* ctx_out_w = (const float*)d_in[3];
    const float* ctx_out_b = (const float*)d_in[4];
    const float* r_w1      = (const float*)d_in[5];
    const float* r_b1      = (const float*)d_in[6];
    const float* r_w2      = (const float*)d_in[7];
    const float* r_b2      = (const float*)d_in[8];
    const float* r_w3      = (const float*)d_in[9];
    const float* r_b3      = (const float*)d_in[10];
    const float* p_in_w    = (const float*)d_in[11];
    const float* p_in_b    = (const float*)d_in[12];
    const float* p_out_w   = (const float*)d_in[13];
    const float* p_out_b   = (const float*)d_in[14];

    float* out  = (float*)d_out;
    float* loss = out + (size_t)TOKENS * DM;
    float* wts  = loss + 1;

    float* F = (float*)d_ws;
    float* qkvbuf   = F;                            // 12,582,912 f32 (router)
    float* obuf     = F + 12582912;                 //  4,194,304 f32 (router)
    float* attended = F;                            // overlays (router only)
    float* h1       = F + 4194304;
    float* h2       = F + 5242880;
    float* scores   = F + 5767168;
    float* freq     = F + 5898240;

    const int M = TOKENS;
    dim3 blk(256);
    const bool big = ws_size >= (size_t)134217728;  // 128 MB

    // ---- Router (fp32-exact) ----
    hipMemsetAsync(freq, 0, NPATH * sizeof(float), stream);
    gemm_f32_nt<0><<<dim3(TD / 128, M / 128), blk, 0, stream>>>(
        x, ctx_in_w, ctx_in_b, qkvbuf, M, TD, DM, DM, DM, TD, 1.f, 0, 0);
    if (big) {
        float* Sbuf = F + 16777216;                 // 64 MB (router phase only)
        gemm_f32_nt<1><<<dim3(8, 8, 16), blk, 0, stream>>>(
            qkvbuf, qkvbuf, nullptr, Sbuf, SEQ, SEQ, 256, TD, TD, SEQ, 0.0625f, 0, 1);
        softmax_rows<<<dim3(16 * SEQ / 4), blk, 0, stream>>>(Sbuf);
        gemm_f32_pv<<<dim3(2, 8, 16), blk, 0, stream>>>(Sbuf, qkvbuf, obuf);
    } else {
        flash_attn<256><<<dim3(SEQ / 32, 8 * 2), blk, 0, stream>>>(qkvbuf, obuf, 2, 1.f / 16.f);
    }
    gemm_f32_nt<1><<<dim3(DM / 128, M / 128), blk, 0, stream>>>(
        obuf, ctx_out_w, ctx_out_b, attended, M, DM, DM, DM, DM, DM, 1.f, 0, 0);
    gemm_f32_nt<1><<<dim3(1, M / 128), blk, 0, stream>>>(
        attended, r_w1, r_b1, h1, M, 128, DM, DM, DM, 128, 1.f, 1, 0);
    gemm_f32<<<dim3(1, M / 64), blk, 0, stream>>>(h1, r_w2, r_b2, h2, M, 64, 128, 1);
    gemm_f32<<<dim3(1, M / 64), blk, 0, stream>>>(h2, r_w3, r_b3, scores, M, NPATH, 64, 0);
    router_epilogue<<<dim3(TOKENS / 256), blk, 0, stream>>>(scores, freq, wts);
    glbl_loss_kernel<<<dim3(1), dim3(64), 0, stream>>>(freq, loss);

    // ---- Pathways (bf16 MFMA) ----
    if (big) {
        __bf16* xb       = (__bf16*)F;                  // [0, 2,097,152)
        __bf16* qkv0     = (__bf16*)(F + 2097152);      // [2.10M, 8.39M)
        __bf16* ob0      = (__bf16*)(F + 8388608);      // [8.39M, 10.49M)
        __bf16* wqkv_all = (__bf16*)(F + 16777216);     // [16.78M, 23.07M)
        __bf16* wout_all = (__bf16*)(F + 23068672);     // [23.07M, 25.17M)
        __bf16* qkv1     = (__bf16*)(F + 25165824);     // [25.17M, 31.46M)
        __bf16* ob1      = (__bf16*)(F + 31457280);     // [31.46M, 33.55M)
        cast_f32_bf16<<<dim3(TOKENS * DM / 4 / 256), blk, 0, stream>>>(x, xb, TOKENS * DM);
        cast_f32_bf16<<<dim3(NPATH * TD * DM / 4 / 256), blk, 0, stream>>>(
            p_in_w, wqkv_all, NPATH * TD * DM);
        cast_f32_bf16<<<dim3(NPATH * DM * DM / 4 / 256), blk, 0, stream>>>(
            p_out_w, wout_all, NPATH * DM * DM);
        for (int k = 0; k < NPATH + 2; ++k) {
            const int pq = (k < NPATH) ? k : -1;
            const int pa = (k >= 1 && k <= NPATH) ? k - 1 : -1;
            const int po = (k >= 2) ? k - 2 : -1;
            const int nA = (pa >= 0) ? 512 : 0;
            const int nQ = (pq >= 0) ? 768 : 0;
            const int nO = (po >= 0) ? 256 : 0;
            fused_path<<<dim3(nA + nQ + nO), blk, 0, stream>>>(
                xb, wqkv_all, p_in_b, wout_all, p_out_b, wts, out,
                qkv0, qkv1, ob0, ob1, nA, nQ, pq, pa, po);
        }
    } else {
        __bf16* xb     = (__bf16*)F;
        __bf16* qkv_b  = (__bf16*)(F + 2097152);
        __bf16* obuf_b = (__bf16*)(F + 8388608);
        __bf16* wqkv_b = (__bf16*)(F + 12582912);
        __bf16* wout_b = (__bf16*)(F + 12976128);
        cast_f32_bf16<<<dim3(TOKENS * DM / 4 / 256), blk, 0, stream>>>(x, xb, TOKENS * DM);
        for (int p = 0; p < NPATH; ++p) {
            cast_f32_bf16<<<dim3(TD * DM / 4 / 256), blk, 0, stream>>>(
                p_in_w + (size_t)p * TD * DM, wqkv_b, TD * DM);
            cast_f32_bf16<<<dim3(DM * DM / 4 / 256), blk, 0, stream>>>(
                p_out_w + (size_t)p * DM * DM, wout_b, DM * DM);
            gemm_bf16_qkv<<<dim3(TD / 128, M / 128), blk, 0, stream>>>(
                xb, wqkv_b, p_in_b + (size_t)p * TD, qkv_b, TD, DM);
            attn_bf16<<<dim3(SEQ / 128, 64), blk, 0, stream>>>(qkv_b, obuf_b);
            gemm_bf16_out<<<dim3(DM / 128, M / 128), blk, 0, stream>>>(
                obuf_b, wout_b, p_out_b + (size_t)p * DM, wts, out, p, p == 0);
        }
    }
}